// Round 1
// baseline (1621.595 us; speedup 1.0000x reference)
//
#include <hip/hip_runtime.h>
#include <hip/hip_fp16.h>

// ---------------------------------------------------------------------------
// QGNN traffic predictor: 2x quaternion GCN (graph-conv GEMMs) + GRU + FC.
// fp32 compute everywhere; fp16 only for large intermediates (S1, feat).
// ---------------------------------------------------------------------------

#define NND 307
#define BBATCH 128
#define LSEQ 12
#define HIDN 64
#define JTOT (BBATCH*LSEQ*HIDN)   // 98304 = columns of the graph-conv GEMMs
#define FSTR 76                   // feat row stride (75 + 1 zero pad)
#define NROWS (NND*BBATCH)        // 39296 GRU rows

// workspace layout (float units)
#define OFF_ANT   0               // a_n transposed: 307*307
#define OFF_DINV  94464           // 307
#define OFF_HAM0  94976           // ham0T [64][4]
#define OFF_HAM1  95232           // ham1  [64][64]
#define OFF_WIHT  99328           // w_ih transposed+padded [76][192]
#define OFF_WHHT  113920          // w_hh transposed [64][192]
#define OFF_S1H   126208          // __half S1 [307][98304] = 15089664 floats
#define OFF_FEATH (126208 + 15089664) // __half feat [39296][12][76] = 17918976 floats
// total = 33,134,848 floats = 132.6 MB

__device__ __forceinline__ float sigmoidf_(float x){ return 1.f/(1.f+expf(-x)); }

// ---------------- adjacency normalization ----------------
__global__ void k_dinv(const float* __restrict__ adj, float* __restrict__ dinv){
  int n = blockIdx.x; int lane = threadIdx.x;
  float s = 0.f;
  for (int m = lane; m < NND; m += 64) s += adj[n*NND+m] + (m==n ? 1.f : 0.f);
  #pragma unroll
  for (int o = 32; o > 0; o >>= 1) s += __shfl_down(s, o);
  if (lane == 0) dinv[n] = 1.f/sqrtf(s);
}

__global__ void k_anT(const float* __restrict__ adj, const float* __restrict__ dinv,
                      float* __restrict__ anT){
  int id = blockIdx.x*256 + threadIdx.x;
  if (id < NND*NND) {
    int n = id / NND, m = id % NND;
    float v = dinv[n] * (adj[id] + (n==m ? 1.f : 0.f)) * dinv[m];
    anT[m*NND + n] = v;   // store transposed for coalesced A-tile loads
  }
}

// ---------------- Hamilton matrices ----------------
__global__ void k_ham(const float* __restrict__ w0, const float* __restrict__ w1,
                      float* __restrict__ ham0T, float* __restrict__ ham1){
  const int  comp[4][4] = {{0,1,2,3},{1,0,3,2},{2,3,0,1},{3,2,1,0}};
  const float sgn[4][4] = {{1.f,1.f,1.f,1.f},{-1.f,1.f,1.f,-1.f},
                           {-1.f,-1.f,1.f,1.f},{-1.f,1.f,-1.f,1.f}};
  int id = blockIdx.x*256 + threadIdx.x;
  if (id < 64) {            // ham0T[d][c] = ham0[c][d], w0 is (1,64)
    int d = id, qb = d>>4, cc = d&15;
    #pragma unroll
    for (int c = 0; c < 4; ++c)
      ham0T[d*4+c] = sgn[c][qb] * w0[comp[c][qb]*16 + cc];
  }
  int id1 = id - 256;
  if (id1 >= 0 && id1 < 4096) { // ham1[d_in][d_out], w1 is (16,64)
    int drow = id1 >> 6, d = id1 & 63;
    int pb = drow>>4, rr = drow&15, qb = d>>4, cc = d&15;
    ham1[id1] = sgn[pb][qb] * w1[rr*64 + comp[pb][qb]*16 + cc];
  }
}

// ---------------- GRU weight transpose (for wave-uniform s_loads) ----------
__global__ void k_wT(const float* __restrict__ w_ih, const float* __restrict__ w_hh,
                     float* __restrict__ wihT, float* __restrict__ whhT){
  int id = blockIdx.x*256 + threadIdx.x;
  if (id < FSTR*192) {                 // [76][192], row 75 zeroed (pad col)
    int k = id / 192, g = id % 192;
    wihT[id] = (k < 75) ? w_ih[g*75 + k] : 0.f;
  } else {
    int id2 = id - FSTR*192;
    if (id2 < 64*192) {
      int k = id2 / 192, g = id2 % 192;
      whhT[id2] = w_hh[g*64 + k];
    }
  }
}

// ---------------- feat extras: speed + time/day embeddings ----------------
__global__ void k_extras(const float* __restrict__ hist, const float* __restrict__ tid_emb,
                         const float* __restrict__ dw_emb, __half* __restrict__ feat){
  int id = blockIdx.x*256 + threadIdx.x;   // over N*B*L
  if (id >= NND*BBATCH*LSEQ) return;
  int n = id / (BBATCH*LSEQ); int rem = id % (BBATCH*LSEQ);
  int b = rem / LSEQ; int l = rem % LSEQ;
  const float* h = hist + ((size_t)(b*LSEQ + l)*NND + n)*4;
  float sp = h[0];
  int ti  = (int)rintf(h[1]*287.f);   // rintf = round-half-even, matches jnp.round
  int dwi = (int)rintf(h[2]*6.f);
  __half* f = feat + ((size_t)(n*BBATCH + b)*LSEQ + l)*FSTR + 64;
  f[0] = __float2half(sp);
  #pragma unroll
  for (int c = 0; c < 5; ++c) f[1+c] = __float2half(tid_emb[ti*5+c]);
  #pragma unroll
  for (int c = 0; c < 5; ++c) f[6+c] = __float2half(dw_emb[dwi*5+c]);
  f[11] = __float2half(0.f);          // pad col 75
}

// ---------------- GEMM1: X1 = a_n @ (hist x ham0); epi: BN0+tanh, @ham1 -> S1
struct SM1 {
  union {
    struct { float As[16][64]; float Bs[16][128]; } m;       // 12 KB main
    struct { float xt[128][68]; float h1[64][64]; } e;       // 51.2 KB epilogue
  } u;
  float ham0T[64][4];
  float sc[64], bi[64];
};

__global__ __launch_bounds__(256) void k_gemm1(
    const float* __restrict__ anT, const float* __restrict__ hist,
    const float* __restrict__ ham0Tg, const float* __restrict__ ham1g,
    const float* __restrict__ bng, const float* __restrict__ bnb,
    const float* __restrict__ bnm, const float* __restrict__ bnv,
    __half* __restrict__ S1){
  __shared__ SM1 s;
  const int t = threadIdx.x;
  const int tx = t & 31, ty = t >> 5;
  const int mt = blockIdx.x / 768, nt = blockIdx.x % 768;
  const int m0 = mt*64, j0 = nt*128;
  if (t < 64) {
    #pragma unroll
    for (int c = 0; c < 4; ++c) s.ham0T[t][c] = ham0Tg[t*4+c];
    float sc = bng[t] / sqrtf(bnv[t] + 1e-5f);
    s.sc[t] = sc; s.bi[t] = bnb[t] - bnm[t]*sc;
  }
  // stage ham1 (region doesn't overlap main-loop tiles)
  for (int i = t; i < 4096; i += 256) (&s.u.e.h1[0][0])[i] = ham1g[i];

  const int kkB = t >> 4;
  const int jlB = (t & 15) * 8;
  const int jg = j0 + jlB;
  const int bB = jg / (LSEQ*HIDN);
  const int lB = (jg / HIDN) % LSEQ;
  const int dB = jg & 63;
  const size_t histBase = ((size_t)(bB*LSEQ + lB)*NND)*4;

  float acc[8][4];
  #pragma unroll
  for (int r = 0; r < 8; ++r)
    #pragma unroll
    for (int c = 0; c < 4; ++c) acc[r][c] = 0.f;

  for (int ks = 0; ks < 20; ++ks) {
    const int k0 = ks*16;
    __syncthreads();
    #pragma unroll
    for (int i = 0; i < 4; ++i) {     // A tile (transposed source, coalesced)
      int kk = (t >> 6) + i*4, mr = t & 63;
      int kg = k0 + kk, mg = m0 + mr;
      s.u.m.As[kk][mr] = (kg < NND && mg < NND) ? anT[kg*NND + mg] : 0.f;
    }
    {                                  // B tile generated: S0 = hist x ham0
      int mg = k0 + kkB;
      float4 h4 = make_float4(0.f,0.f,0.f,0.f);
      if (mg < NND) h4 = *(const float4*)(hist + histBase + (size_t)mg*4);
      #pragma unroll
      for (int u = 0; u < 8; ++u) {
        int d = dB + u;
        s.u.m.Bs[kkB][jlB+u] =
          h4.x*s.ham0T[d][0] + h4.y*s.ham0T[d][1] + h4.z*s.ham0T[d][2] + h4.w*s.ham0T[d][3];
      }
    }
    __syncthreads();
    #pragma unroll
    for (int kk = 0; kk < 16; ++kk) {
      float4 a0 = *(const float4*)&s.u.m.As[kk][ty*8];
      float4 a1 = *(const float4*)&s.u.m.As[kk][ty*8+4];
      float4 b0 = *(const float4*)&s.u.m.Bs[kk][tx*4];
      float av[8] = {a0.x,a0.y,a0.z,a0.w,a1.x,a1.y,a1.z,a1.w};
      float bv[4] = {b0.x,b0.y,b0.z,b0.w};
      #pragma unroll
      for (int r = 0; r < 8; ++r)
        #pragma unroll
        for (int c = 0; c < 4; ++c)
          acc[r][c] = fmaf(av[r], bv[c], acc[r][c]);
    }
  }
  __syncthreads();
  // BN0 + tanh -> xt (transposed in LDS)
  #pragma unroll
  for (int r = 0; r < 8; ++r)
    #pragma unroll
    for (int c = 0; c < 4; ++c) {
      int d = (tx*4 + c) & 63;
      s.u.e.xt[tx*4+c][ty*8+r] = tanhf(acc[r][c]*s.sc[d] + s.bi[d]);
    }
  __syncthreads();
  // second small GEMM: S1 = x1 @ ham1 (per 64-d group)
  float e[8][4];
  #pragma unroll
  for (int r=0;r<8;++r)
    #pragma unroll
    for (int c=0;c<4;++c) e[r][c]=0.f;
  const int g64 = (tx >= 16) ? 64 : 0;
  const int dp = (tx & 15)*4;
  #pragma unroll 8
  for (int dd = 0; dd < 64; ++dd) {
    float4 xa0 = *(const float4*)&s.u.e.xt[g64+dd][ty*8];
    float4 xa1 = *(const float4*)&s.u.e.xt[g64+dd][ty*8+4];
    float4 hb  = *(const float4*)&s.u.e.h1[dd][dp];
    float xv[8] = {xa0.x,xa0.y,xa0.z,xa0.w,xa1.x,xa1.y,xa1.z,xa1.w};
    float hv[4] = {hb.x,hb.y,hb.z,hb.w};
    #pragma unroll
    for (int r=0;r<8;++r)
      #pragma unroll
      for (int c=0;c<4;++c)
        e[r][c] = fmaf(xv[r], hv[c], e[r][c]);
  }
  #pragma unroll
  for (int r = 0; r < 8; ++r) {
    int n = m0 + ty*8 + r;
    if (n < NND) {
      __half2 p0 = __floats2half2_rn(e[r][0], e[r][1]);
      __half2 p1 = __floats2half2_rn(e[r][2], e[r][3]);
      __half2* dst = (__half2*)(S1 + (size_t)n*JTOT + j0 + tx*4);
      dst[0] = p0; dst[1] = p1;
    }
  }
}

// ---------------- GEMM2: X2 = a_n @ S1; epi: BN1+tanh -> feat[:,:,0:64] ----
__global__ __launch_bounds__(256) void k_gemm2(
    const float* __restrict__ anT, const __half* __restrict__ S1,
    const float* __restrict__ bng, const float* __restrict__ bnb,
    const float* __restrict__ bnm, const float* __restrict__ bnv,
    __half* __restrict__ feat){
  __shared__ float As[16][64];
  __shared__ float Bs[16][128];
  __shared__ float sc_[64], bi_[64];
  const int t = threadIdx.x, tx = t & 31, ty = t >> 5;
  const int mt = blockIdx.x / 768, nt = blockIdx.x % 768;
  const int m0 = mt*64, j0 = nt*128;
  if (t < 64) {
    float sc = bng[64+t] / sqrtf(bnv[64+t] + 1e-5f);
    sc_[t] = sc; bi_[t] = bnb[64+t] - bnm[64+t]*sc;
  }
  const int kkB = t >> 4, jlB = (t & 15)*8;
  float acc[8][4];
  #pragma unroll
  for (int r = 0; r < 8; ++r)
    #pragma unroll
    for (int c = 0; c < 4; ++c) acc[r][c] = 0.f;

  for (int ks = 0; ks < 20; ++ks) {
    const int k0 = ks*16;
    __syncthreads();
    #pragma unroll
    for (int i = 0; i < 4; ++i) {
      int kk = (t>>6) + i*4, mr = t & 63;
      int kg = k0+kk, mg = m0+mr;
      As[kk][mr] = (kg < NND && mg < NND) ? anT[kg*NND+mg] : 0.f;
    }
    {
      int kg = k0 + kkB;
      float4 raw = make_float4(0.f,0.f,0.f,0.f);
      if (kg < NND) raw = *(const float4*)(S1 + (size_t)kg*JTOT + j0 + jlB);
      const __half2* hp = (const __half2*)&raw;
      #pragma unroll
      for (int u = 0; u < 4; ++u) {
        float2 f = __half22float2(hp[u]);
        Bs[kkB][jlB + 2*u] = f.x; Bs[kkB][jlB + 2*u + 1] = f.y;
      }
    }
    __syncthreads();
    #pragma unroll
    for (int kk = 0; kk < 16; ++kk) {
      float4 a0 = *(const float4*)&As[kk][ty*8];
      float4 a1 = *(const float4*)&As[kk][ty*8+4];
      float4 b0 = *(const float4*)&Bs[kk][tx*4];
      float av[8] = {a0.x,a0.y,a0.z,a0.w,a1.x,a1.y,a1.z,a1.w};
      float bv[4] = {b0.x,b0.y,b0.z,b0.w};
      #pragma unroll
      for (int r = 0; r < 8; ++r)
        #pragma unroll
        for (int c = 0; c < 4; ++c)
          acc[r][c] = fmaf(av[r], bv[c], acc[r][c]);
    }
  }
  // epilogue: BN1 + tanh -> feat cols [d0, d0+4)
  const int jcb = j0 + tx*4;
  const int bo = jcb / (LSEQ*HIDN);
  const int lo = (jcb / HIDN) % LSEQ;
  const int d0 = (tx*4) & 63;
  #pragma unroll
  for (int r = 0; r < 8; ++r) {
    int n = m0 + ty*8 + r;
    if (n < NND) {
      float v0 = tanhf(acc[r][0]*sc_[d0+0] + bi_[d0+0]);
      float v1 = tanhf(acc[r][1]*sc_[d0+1] + bi_[d0+1]);
      float v2 = tanhf(acc[r][2]*sc_[d0+2] + bi_[d0+2]);
      float v3 = tanhf(acc[r][3]*sc_[d0+3] + bi_[d0+3]);
      __half2 p0 = __floats2half2_rn(v0,v1), p1 = __floats2half2_rn(v2,v3);
      __half2* dst = (__half2*)(feat + ((size_t)(n*BBATCH + bo)*LSEQ + lo)*FSTR + d0);
      dst[0]=p0; dst[1]=p1;
    }
  }
}

// ---------------- GRU (12 steps) + ReLU + FC head ----------------
// block = 256 thr = 4 waves; lane = row (64 rows/block); wave w owns d in [16w,16w+16)
__global__ __launch_bounds__(256) void k_gru(
    const __half* __restrict__ feat, const float* __restrict__ wihT,
    const float* __restrict__ whhT, const float* __restrict__ b_ih,
    const float* __restrict__ b_hh, const float* __restrict__ fc_w,
    const float* __restrict__ fc_b, float* __restrict__ out){
  __shared__ float hT[64][64];   // [d][row] — conflict-free lane-contiguous
  __shared__ float red[4][64];
  const int lane = threadIdx.x & 63;
  const int wv = threadIdx.x >> 6;
  const int dbase = __builtin_amdgcn_readfirstlane(wv) * 16; // force SGPR
  const int row = blockIdx.x*64 + lane;
  for (int i = threadIdx.x; i < 64*64; i += 256) (&hT[0][0])[i] = 0.f;
  __syncthreads();
  const __half* xrow = feat + (size_t)row * (LSEQ*FSTR);

  for (int tstep = 0; tstep < 12; ++tstep) {
    float aR[16], aZ[16], aI[16], aH[16];
    #pragma unroll
    for (int i = 0; i < 16; ++i) { aR[i]=0.f; aZ[i]=0.f; aI[i]=0.f; aH[i]=0.f; }
    // input GEMV: k over 76 (col 75 zero-padded both sides)
    const __half2* xp = (const __half2*)(xrow + (size_t)tstep*FSTR);
    for (int kc = 0; kc < 19; ++kc) {
      float2 f0 = __half22float2(xp[2*kc]);
      float2 f1 = __half22float2(xp[2*kc+1]);
      float xs[4] = {f0.x, f0.y, f1.x, f1.y};
      #pragma unroll
      for (int kk = 0; kk < 4; ++kk) {
        const float* wr = wihT + (kc*4+kk)*192 + dbase;  // wave-uniform -> s_load
        float xv = xs[kk];
        #pragma unroll
        for (int dl = 0; dl < 16; ++dl) {
          aR[dl] = fmaf(wr[dl],     xv, aR[dl]);
          aZ[dl] = fmaf(wr[64+dl],  xv, aZ[dl]);
          aI[dl] = fmaf(wr[128+dl], xv, aI[dl]);
        }
      }
    }
    // hidden GEMV: k over 64
    for (int k = 0; k < 64; ++k) {
      float hv = hT[k][lane];
      const float* wr = whhT + k*192 + dbase;
      #pragma unroll
      for (int dl = 0; dl < 16; ++dl) {
        aR[dl] = fmaf(wr[dl],     hv, aR[dl]);
        aZ[dl] = fmaf(wr[64+dl],  hv, aZ[dl]);
        aH[dl] = fmaf(wr[128+dl], hv, aH[dl]);
      }
    }
    float hnew[16];
    #pragma unroll
    for (int dl = 0; dl < 16; ++dl) {
      int d = dbase + dl;
      float r  = sigmoidf_(aR[dl] + b_ih[d]     + b_hh[d]);
      float z  = sigmoidf_(aZ[dl] + b_ih[64+d]  + b_hh[64+d]);
      float nc = tanhf(aI[dl] + b_ih[128+d] + r*(aH[dl] + b_hh[128+d]));
      hnew[dl] = (1.f - z)*nc + z*hT[d][lane];
    }
    __syncthreads();                 // all h_old reads done
    #pragma unroll
    for (int dl = 0; dl < 16; ++dl) hT[dbase+dl][lane] = hnew[dl];
    __syncthreads();
    if (tstep >= 9) {                // fused ReLU + FC head
      float part = 0.f;
      #pragma unroll
      for (int dl = 0; dl < 16; ++dl)
        part = fmaf(fmaxf(hnew[dl], 0.f), fc_w[dbase+dl], part);
      red[wv][lane] = part;
      __syncthreads();
      if (wv == 0) {
        float sres = red[0][lane]+red[1][lane]+red[2][lane]+red[3][lane] + fc_b[0];
        int nn = row >> 7, bb = row & 127;     // row = n*128 + b
        out[(bb*3 + (tstep-9))*NND + nn] = sres;
      }
      __syncthreads();
    }
  }
}

// ---------------------------------------------------------------------------
extern "C" void kernel_launch(void* const* d_in, const int* in_sizes, int n_in,
                              void* d_out, int out_size, void* d_ws, size_t ws_size,
                              hipStream_t stream) {
  const float* hist    = (const float*)d_in[0];
  const float* adj     = (const float*)d_in[1];
  const float* w0      = (const float*)d_in[2];
  const float* w1      = (const float*)d_in[3];
  const float* bng     = (const float*)d_in[4];
  const float* bnb     = (const float*)d_in[5];
  const float* bnm     = (const float*)d_in[6];
  const float* bnv     = (const float*)d_in[7];
  const float* tid_emb = (const float*)d_in[8];
  const float* dw_emb  = (const float*)d_in[9];
  const float* w_ih    = (const float*)d_in[10];
  const float* w_hh    = (const float*)d_in[11];
  const float* b_ih    = (const float*)d_in[12];
  const float* b_hh    = (const float*)d_in[13];
  const float* fc_w    = (const float*)d_in[14];
  const float* fc_b    = (const float*)d_in[15];

  float* wsf   = (float*)d_ws;
  float* anT   = wsf + OFF_ANT;
  float* dinv  = wsf + OFF_DINV;
  float* ham0T = wsf + OFF_HAM0;
  float* ham1  = wsf + OFF_HAM1;
  float* wihT  = wsf + OFF_WIHT;
  float* whhT  = wsf + OFF_WHHT;
  __half* S1h   = (__half*)(wsf + OFF_S1H);
  __half* feath = (__half*)(wsf + OFF_FEATH);
  float* outp  = (float*)d_out;

  k_dinv  <<<NND, 64, 0, stream>>>(adj, dinv);
  k_anT   <<<(NND*NND + 255)/256, 256, 0, stream>>>(adj, dinv, anT);
  k_ham   <<<17, 256, 0, stream>>>(w0, w1, ham0T, ham1);
  k_wT    <<<(FSTR*192 + 64*192)/256, 256, 0, stream>>>(w_ih, w_hh, wihT, whhT);
  k_extras<<<(NND*BBATCH*LSEQ)/256, 256, 0, stream>>>(hist, tid_emb, dw_emb, feath);
  k_gemm1 <<<5*768, 256, 0, stream>>>(anT, hist, ham0T, ham1, bng, bnb, bnm, bnv, S1h);
  k_gemm2 <<<5*768, 256, 0, stream>>>(anT, S1h, bng, bnb, bnm, bnv, feath);
  k_gru   <<<NROWS/64, 256, 0, stream>>>(feath, wihT, whhT, b_ih, b_hh, fc_w, fc_b, outp);
}

// Round 2
// 1315.115 us; speedup vs baseline: 1.2330x; 1.2330x over previous
//
#include <hip/hip_runtime.h>
#include <hip/hip_fp16.h>

// ---------------------------------------------------------------------------
// QGNN traffic predictor: 2x quaternion GCN (graph-conv GEMMs) + GRU + FC.
// fp32 compute everywhere; fp16 only for large intermediates (S1, feat).
// R2: conflict-free LDS staging (contiguous b128 writes), ham0 in registers,
//     row-major epilogue transpose with broadcast reads.
// ---------------------------------------------------------------------------

#define NND 307
#define BBATCH 128
#define LSEQ 12
#define HIDN 64
#define JTOT (BBATCH*LSEQ*HIDN)   // 98304 = columns of the graph-conv GEMMs
#define FSTR 76                   // feat row stride (75 + 1 zero pad)
#define NROWS (NND*BBATCH)        // 39296 GRU rows

// workspace layout (float units)
#define OFF_ANT   0               // a_n transposed: 307*307
#define OFF_DINV  94464           // 307
#define OFF_HAM0  94976           // ham0T [64][4]
#define OFF_HAM1  95232           // ham1  [64][64]
#define OFF_WIHT  99328           // w_ih transposed+padded [76][192]
#define OFF_WHHT  113920          // w_hh transposed [64][192]
#define OFF_S1H   126208          // __half S1 [307][98304] = 15089664 floats
#define OFF_FEATH (126208 + 15089664) // __half feat [39296][12][76] = 17918976 floats

__device__ __forceinline__ float sigmoidf_(float x){ return 1.f/(1.f+expf(-x)); }

// ---------------- adjacency normalization ----------------
__global__ void k_dinv(const float* __restrict__ adj, float* __restrict__ dinv){
  int n = blockIdx.x; int lane = threadIdx.x;
  float s = 0.f;
  for (int m = lane; m < NND; m += 64) s += adj[n*NND+m] + (m==n ? 1.f : 0.f);
  #pragma unroll
  for (int o = 32; o > 0; o >>= 1) s += __shfl_down(s, o);
  if (lane == 0) dinv[n] = 1.f/sqrtf(s);
}

__global__ void k_anT(const float* __restrict__ adj, const float* __restrict__ dinv,
                      float* __restrict__ anT){
  int id = blockIdx.x*256 + threadIdx.x;
  if (id < NND*NND) {
    int n = id / NND, m = id % NND;
    float v = dinv[n] * (adj[id] + (n==m ? 1.f : 0.f)) * dinv[m];
    anT[m*NND + n] = v;   // store transposed for coalesced A-tile loads
  }
}

// ---------------- Hamilton matrices ----------------
__global__ void k_ham(const float* __restrict__ w0, const float* __restrict__ w1,
                      float* __restrict__ ham0T, float* __restrict__ ham1){
  const int  comp[4][4] = {{0,1,2,3},{1,0,3,2},{2,3,0,1},{3,2,1,0}};
  const float sgn[4][4] = {{1.f,1.f,1.f,1.f},{-1.f,1.f,1.f,-1.f},
                           {-1.f,-1.f,1.f,1.f},{-1.f,1.f,-1.f,1.f}};
  int id = blockIdx.x*256 + threadIdx.x;
  if (id < 64) {            // ham0T[d][c] = ham0[c][d], w0 is (1,64)
    int d = id, qb = d>>4, cc = d&15;
    #pragma unroll
    for (int c = 0; c < 4; ++c)
      ham0T[d*4+c] = sgn[c][qb] * w0[comp[c][qb]*16 + cc];
  }
  int id1 = id - 256;
  if (id1 >= 0 && id1 < 4096) { // ham1[d_in][d_out], w1 is (16,64)
    int drow = id1 >> 6, d = id1 & 63;
    int pb = drow>>4, rr = drow&15, qb = d>>4, cc = d&15;
    ham1[id1] = sgn[pb][qb] * w1[rr*64 + comp[pb][qb]*16 + cc];
  }
}

// ---------------- GRU weight transpose (for wave-uniform s_loads) ----------
__global__ void k_wT(const float* __restrict__ w_ih, const float* __restrict__ w_hh,
                     float* __restrict__ wihT, float* __restrict__ whhT){
  int id = blockIdx.x*256 + threadIdx.x;
  if (id < FSTR*192) {                 // [76][192], row 75 zeroed (pad col)
    int k = id / 192, g = id % 192;
    wihT[id] = (k < 75) ? w_ih[g*75 + k] : 0.f;
  } else {
    int id2 = id - FSTR*192;
    if (id2 < 64*192) {
      int k = id2 / 192, g = id2 % 192;
      whhT[id2] = w_hh[g*64 + k];
    }
  }
}

// ---------------- feat extras: speed + time/day embeddings ----------------
__global__ void k_extras(const float* __restrict__ hist, const float* __restrict__ tid_emb,
                         const float* __restrict__ dw_emb, __half* __restrict__ feat){
  int id = blockIdx.x*256 + threadIdx.x;   // over N*B*L
  if (id >= NND*BBATCH*LSEQ) return;
  int n = id / (BBATCH*LSEQ); int rem = id % (BBATCH*LSEQ);
  int b = rem / LSEQ; int l = rem % LSEQ;
  const float* h = hist + ((size_t)(b*LSEQ + l)*NND + n)*4;
  float sp = h[0];
  int ti  = (int)rintf(h[1]*287.f);   // rintf = round-half-even, matches jnp.round
  int dwi = (int)rintf(h[2]*6.f);
  __half* f = feat + ((size_t)(n*BBATCH + b)*LSEQ + l)*FSTR + 64;
  f[0] = __float2half(sp);
  #pragma unroll
  for (int c = 0; c < 5; ++c) f[1+c] = __float2half(tid_emb[ti*5+c]);
  #pragma unroll
  for (int c = 0; c < 5; ++c) f[6+c] = __float2half(dw_emb[dwi*5+c]);
  f[11] = __float2half(0.f);          // pad col 75
}

// ---------------- GEMM1: X1 = a_n @ (hist x ham0); epi: BN0+tanh, @ham1 -> S1
struct SM1 {
  union {
    struct { float As[16][64]; float Bs[16][128]; } m;       // 12 KB main
    struct { float xt2[64][128]; float h1[64][64]; } e;      // 48 KB epilogue
  } u;
  float sc[64], bi[64];
};

__global__ __launch_bounds__(256) void k_gemm1(
    const float* __restrict__ anT, const float* __restrict__ hist,
    const float* __restrict__ ham0Tg, const float* __restrict__ ham1g,
    const float* __restrict__ bng, const float* __restrict__ bnb,
    const float* __restrict__ bnm, const float* __restrict__ bnv,
    __half* __restrict__ S1){
  __shared__ SM1 s;
  const int t = threadIdx.x;
  const int tx = t & 31, ty = t >> 5;
  const int mt = blockIdx.x / 768, nt = blockIdx.x % 768;
  const int m0 = mt*64, j0 = nt*128;
  if (t < 64) {
    float sc = bng[t] / sqrtf(bnv[t] + 1e-5f);
    s.sc[t] = sc; s.bi[t] = bnb[t] - bnm[t]*sc;
  }
  // stage ham1 once (e.h1 at float-offset 8192 > 3072 used by main tiles)
  for (int i = t; i < 4096; i += 256) (&s.u.e.h1[0][0])[i] = ham1g[i];

  // ---- B-staging mapping: lane l of wave w writes rows 4w+(l>>5), +2; cols 4(l&31)
  const int lB = t & 63, wB = t >> 6;
  const int kkA = 4*wB + (lB >> 5);          // first staged row (second = +2)
  const int jc  = (lB & 31) * 4;             // col base within 128-tile
  const int jg  = j0 + jc;
  const int bB  = jg / (LSEQ*HIDN);
  const int lqB = (jg / HIDN) % LSEQ;
  const int d0B = jc & 63;
  const size_t histBase = ((size_t)(bB*LSEQ + lqB)*NND)*4;
  float4 h0a[4];                              // ham0T rows d0B..d0B+3 in registers
  #pragma unroll
  for (int u = 0; u < 4; ++u) h0a[u] = *(const float4*)(ham0Tg + (d0B+u)*4);

  float acc[8][4];
  #pragma unroll
  for (int r = 0; r < 8; ++r)
    #pragma unroll
    for (int c = 0; c < 4; ++c) acc[r][c] = 0.f;

  for (int ks = 0; ks < 20; ++ks) {
    const int k0 = ks*16;
    __syncthreads();
    #pragma unroll
    for (int i = 0; i < 4; ++i) {     // A tile (transposed source, coalesced)
      int kk = (t >> 6) + i*4, mr = t & 63;
      int kg = k0 + kk, mg = m0 + mr;
      s.u.m.As[kk][mr] = (kg < NND && mg < NND) ? anT[kg*NND + mg] : 0.f;
    }
    {                                  // B tile: S0 = hist x ham0, built in regs
      int mg0 = k0 + kkA, mg1 = mg0 + 2;
      float4 hA = make_float4(0.f,0.f,0.f,0.f), hB = hA;
      if (mg0 < NND) hA = *(const float4*)(hist + histBase + (size_t)mg0*4);
      if (mg1 < NND) hB = *(const float4*)(hist + histBase + (size_t)mg1*4);
      float4 v0, v1;
      v0.x = hA.x*h0a[0].x + hA.y*h0a[0].y + hA.z*h0a[0].z + hA.w*h0a[0].w;
      v0.y = hA.x*h0a[1].x + hA.y*h0a[1].y + hA.z*h0a[1].z + hA.w*h0a[1].w;
      v0.z = hA.x*h0a[2].x + hA.y*h0a[2].y + hA.z*h0a[2].z + hA.w*h0a[2].w;
      v0.w = hA.x*h0a[3].x + hA.y*h0a[3].y + hA.z*h0a[3].z + hA.w*h0a[3].w;
      v1.x = hB.x*h0a[0].x + hB.y*h0a[0].y + hB.z*h0a[0].z + hB.w*h0a[0].w;
      v1.y = hB.x*h0a[1].x + hB.y*h0a[1].y + hB.z*h0a[1].z + hB.w*h0a[1].w;
      v1.z = hB.x*h0a[2].x + hB.y*h0a[2].y + hB.z*h0a[2].z + hB.w*h0a[2].w;
      v1.w = hB.x*h0a[3].x + hB.y*h0a[3].y + hB.z*h0a[3].z + hB.w*h0a[3].w;
      *(float4*)&s.u.m.Bs[kkA][jc]   = v0;   // wave-contiguous 1KB b128 writes
      *(float4*)&s.u.m.Bs[kkA+2][jc] = v1;
    }
    __syncthreads();
    #pragma unroll
    for (int kk = 0; kk < 16; ++kk) {
      float4 a0 = *(const float4*)&s.u.m.As[kk][ty*8];
      float4 a1 = *(const float4*)&s.u.m.As[kk][ty*8+4];
      float4 b0 = *(const float4*)&s.u.m.Bs[kk][tx*4];
      float av[8] = {a0.x,a0.y,a0.z,a0.w,a1.x,a1.y,a1.z,a1.w};
      float bv[4] = {b0.x,b0.y,b0.z,b0.w};
      #pragma unroll
      for (int r = 0; r < 8; ++r)
        #pragma unroll
        for (int c = 0; c < 4; ++c)
          acc[r][c] = fmaf(av[r], bv[c], acc[r][c]);
    }
  }
  __syncthreads();
  // BN0 + tanh -> xt2[n][j] row-major (contiguous float4 writes, no conflicts)
  const int d0e = (tx*4) & 63;
  #pragma unroll
  for (int r = 0; r < 8; ++r) {
    float4 v;
    v.x = tanhf(acc[r][0]*s.sc[d0e+0] + s.bi[d0e+0]);
    v.y = tanhf(acc[r][1]*s.sc[d0e+1] + s.bi[d0e+1]);
    v.z = tanhf(acc[r][2]*s.sc[d0e+2] + s.bi[d0e+2]);
    v.w = tanhf(acc[r][3]*s.sc[d0e+3] + s.bi[d0e+3]);
    *(float4*)&s.u.e.xt2[ty*8+r][tx*4] = v;
  }
  __syncthreads();
  // second small GEMM: S1 = x1 @ ham1 (per 64-d group); xv reads are broadcast
  float e[8][4];
  #pragma unroll
  for (int r=0;r<8;++r)
    #pragma unroll
    for (int c=0;c<4;++c) e[r][c]=0.f;
  const int g64 = (tx >= 16) ? 64 : 0;
  const int dp = (tx & 15)*4;
  #pragma unroll 4
  for (int dd = 0; dd < 64; ++dd) {
    float4 hb = *(const float4*)&s.u.e.h1[dd][dp];
    #pragma unroll
    for (int r = 0; r < 8; ++r) {
      float xv = s.u.e.xt2[ty*8+r][g64+dd];
      e[r][0] = fmaf(xv, hb.x, e[r][0]);
      e[r][1] = fmaf(xv, hb.y, e[r][1]);
      e[r][2] = fmaf(xv, hb.z, e[r][2]);
      e[r][3] = fmaf(xv, hb.w, e[r][3]);
    }
  }
  #pragma unroll
  for (int r = 0; r < 8; ++r) {
    int n = m0 + ty*8 + r;
    if (n < NND) {
      __half2 p0 = __floats2half2_rn(e[r][0], e[r][1]);
      __half2 p1 = __floats2half2_rn(e[r][2], e[r][3]);
      __half2* dst = (__half2*)(S1 + (size_t)n*JTOT + j0 + tx*4);
      dst[0] = p0; dst[1] = p1;
    }
  }
}

// ---------------- GEMM2: X2 = a_n @ S1; epi: BN1+tanh -> feat[:,:,0:64] ----
__global__ __launch_bounds__(256) void k_gemm2(
    const float* __restrict__ anT, const __half* __restrict__ S1,
    const float* __restrict__ bng, const float* __restrict__ bnb,
    const float* __restrict__ bnm, const float* __restrict__ bnv,
    __half* __restrict__ feat){
  __shared__ float As[16][64];
  __shared__ float Bs[16][128];
  __shared__ float sc_[64], bi_[64];
  const int t = threadIdx.x, tx = t & 31, ty = t >> 5;
  const int mt = blockIdx.x / 768, nt = blockIdx.x % 768;
  const int m0 = mt*64, j0 = nt*128;
  if (t < 64) {
    float sc = bng[64+t] / sqrtf(bnv[64+t] + 1e-5f);
    sc_[t] = sc; bi_[t] = bnb[64+t] - bnm[64+t]*sc;
  }
  const int lB = t & 63, wB = t >> 6;
  const int kkA = 4*wB + (lB >> 5);
  const int jc  = (lB & 31) * 4;
  float acc[8][4];
  #pragma unroll
  for (int r = 0; r < 8; ++r)
    #pragma unroll
    for (int c = 0; c < 4; ++c) acc[r][c] = 0.f;

  for (int ks = 0; ks < 20; ++ks) {
    const int k0 = ks*16;
    __syncthreads();
    #pragma unroll
    for (int i = 0; i < 4; ++i) {
      int kk = (t>>6) + i*4, mr = t & 63;
      int kg = k0+kk, mg = m0+mr;
      As[kk][mr] = (kg < NND && mg < NND) ? anT[kg*NND+mg] : 0.f;
    }
    {
      int kg0 = k0 + kkA, kg1 = kg0 + 2;
      uint2 r0 = make_uint2(0u,0u), r1 = make_uint2(0u,0u);
      if (kg0 < NND) r0 = *(const uint2*)(S1 + (size_t)kg0*JTOT + j0 + jc);
      if (kg1 < NND) r1 = *(const uint2*)(S1 + (size_t)kg1*JTOT + j0 + jc);
      float2 a0 = __half22float2(*(__half2*)&r0.x);
      float2 a1 = __half22float2(*(__half2*)&r0.y);
      float2 b0 = __half22float2(*(__half2*)&r1.x);
      float2 b1 = __half22float2(*(__half2*)&r1.y);
      *(float4*)&Bs[kkA][jc]   = make_float4(a0.x, a0.y, a1.x, a1.y);
      *(float4*)&Bs[kkA+2][jc] = make_float4(b0.x, b0.y, b1.x, b1.y);
    }
    __syncthreads();
    #pragma unroll
    for (int kk = 0; kk < 16; ++kk) {
      float4 a0 = *(const float4*)&As[kk][ty*8];
      float4 a1 = *(const float4*)&As[kk][ty*8+4];
      float4 b0 = *(const float4*)&Bs[kk][tx*4];
      float av[8] = {a0.x,a0.y,a0.z,a0.w,a1.x,a1.y,a1.z,a1.w};
      float bv[4] = {b0.x,b0.y,b0.z,b0.w};
      #pragma unroll
      for (int r = 0; r < 8; ++r)
        #pragma unroll
        for (int c = 0; c < 4; ++c)
          acc[r][c] = fmaf(av[r], bv[c], acc[r][c]);
    }
  }
  // epilogue: BN1 + tanh -> feat cols [d0, d0+4)
  const int jcb = j0 + tx*4;
  const int bo = jcb / (LSEQ*HIDN);
  const int lo = (jcb / HIDN) % LSEQ;
  const int d0 = (tx*4) & 63;
  #pragma unroll
  for (int r = 0; r < 8; ++r) {
    int n = m0 + ty*8 + r;
    if (n < NND) {
      float v0 = tanhf(acc[r][0]*sc_[d0+0] + bi_[d0+0]);
      float v1 = tanhf(acc[r][1]*sc_[d0+1] + bi_[d0+1]);
      float v2 = tanhf(acc[r][2]*sc_[d0+2] + bi_[d0+2]);
      float v3 = tanhf(acc[r][3]*sc_[d0+3] + bi_[d0+3]);
      __half2 p0 = __floats2half2_rn(v0,v1), p1 = __floats2half2_rn(v2,v3);
      __half2* dst = (__half2*)(feat + ((size_t)(n*BBATCH + bo)*LSEQ + lo)*FSTR + d0);
      dst[0]=p0; dst[1]=p1;
    }
  }
}

// ---------------- GRU (12 steps) + ReLU + FC head ----------------
// block = 256 thr = 4 waves; lane = row (64 rows/block); wave w owns d in [16w,16w+16)
__global__ __launch_bounds__(256) void k_gru(
    const __half* __restrict__ feat, const float* __restrict__ wihT,
    const float* __restrict__ whhT, const float* __restrict__ b_ih,
    const float* __restrict__ b_hh, const float* __restrict__ fc_w,
    const float* __restrict__ fc_b, float* __restrict__ out){
  __shared__ float hT[64][64];   // [d][row] — conflict-free lane-contiguous
  __shared__ float red[4][64];
  const int lane = threadIdx.x & 63;
  const int wv = threadIdx.x >> 6;
  const int dbase = __builtin_amdgcn_readfirstlane(wv) * 16; // force SGPR
  const int row = blockIdx.x*64 + lane;
  for (int i = threadIdx.x; i < 64*64; i += 256) (&hT[0][0])[i] = 0.f;
  __syncthreads();
  const __half* xrow = feat + (size_t)row * (LSEQ*FSTR);

  for (int tstep = 0; tstep < 12; ++tstep) {
    float aR[16], aZ[16], aI[16], aH[16];
    #pragma unroll
    for (int i = 0; i < 16; ++i) { aR[i]=0.f; aZ[i]=0.f; aI[i]=0.f; aH[i]=0.f; }
    // input GEMV: k over 76 (col 75 zero-padded both sides)
    const __half2* xp = (const __half2*)(xrow + (size_t)tstep*FSTR);
    for (int kc = 0; kc < 19; ++kc) {
      float2 f0 = __half22float2(xp[2*kc]);
      float2 f1 = __half22float2(xp[2*kc+1]);
      float xs[4] = {f0.x, f0.y, f1.x, f1.y};
      #pragma unroll
      for (int kk = 0; kk < 4; ++kk) {
        const float* wr = wihT + (kc*4+kk)*192 + dbase;  // wave-uniform -> s_load
        float xv = xs[kk];
        #pragma unroll
        for (int dl = 0; dl < 16; ++dl) {
          aR[dl] = fmaf(wr[dl],     xv, aR[dl]);
          aZ[dl] = fmaf(wr[64+dl],  xv, aZ[dl]);
          aI[dl] = fmaf(wr[128+dl], xv, aI[dl]);
        }
      }
    }
    // hidden GEMV: k over 64
    for (int k = 0; k < 64; ++k) {
      float hv = hT[k][lane];
      const float* wr = whhT + k*192 + dbase;
      #pragma unroll
      for (int dl = 0; dl < 16; ++dl) {
        aR[dl] = fmaf(wr[dl],     hv, aR[dl]);
        aZ[dl] = fmaf(wr[64+dl],  hv, aZ[dl]);
        aH[dl] = fmaf(wr[128+dl], hv, aH[dl]);
      }
    }
    float hnew[16];
    #pragma unroll
    for (int dl = 0; dl < 16; ++dl) {
      int d = dbase + dl;
      float r  = sigmoidf_(aR[dl] + b_ih[d]     + b_hh[d]);
      float z  = sigmoidf_(aZ[dl] + b_ih[64+d]  + b_hh[64+d]);
      float nc = tanhf(aI[dl] + b_ih[128+d] + r*(aH[dl] + b_hh[128+d]));
      hnew[dl] = (1.f - z)*nc + z*hT[d][lane];
    }
    __syncthreads();                 // all h_old reads done
    #pragma unroll
    for (int dl = 0; dl < 16; ++dl) hT[dbase+dl][lane] = hnew[dl];
    __syncthreads();
    if (tstep >= 9) {                // fused ReLU + FC head
      float part = 0.f;
      #pragma unroll
      for (int dl = 0; dl < 16; ++dl)
        part = fmaf(fmaxf(hnew[dl], 0.f), fc_w[dbase+dl], part);
      red[wv][lane] = part;
      __syncthreads();
      if (wv == 0) {
        float sres = red[0][lane]+red[1][lane]+red[2][lane]+red[3][lane] + fc_b[0];
        int nn = row >> 7, bb = row & 127;     // row = n*128 + b
        out[(bb*3 + (tstep-9))*NND + nn] = sres;
      }
      __syncthreads();
    }
  }
}

// ---------------------------------------------------------------------------
extern "C" void kernel_launch(void* const* d_in, const int* in_sizes, int n_in,
                              void* d_out, int out_size, void* d_ws, size_t ws_size,
                              hipStream_t stream) {
  const float* hist    = (const float*)d_in[0];
  const float* adj     = (const float*)d_in[1];
  const float* w0      = (const float*)d_in[2];
  const float* w1      = (const float*)d_in[3];
  const float* bng     = (const float*)d_in[4];
  const float* bnb     = (const float*)d_in[5];
  const float* bnm     = (const float*)d_in[6];
  const float* bnv     = (const float*)d_in[7];
  const float* tid_emb = (const float*)d_in[8];
  const float* dw_emb  = (const float*)d_in[9];
  const float* w_ih    = (const float*)d_in[10];
  const float* w_hh    = (const float*)d_in[11];
  const float* b_ih    = (const float*)d_in[12];
  const float* b_hh    = (const float*)d_in[13];
  const float* fc_w    = (const float*)d_in[14];
  const float* fc_b    = (const float*)d_in[15];

  float* wsf   = (float*)d_ws;
  float* anT   = wsf + OFF_ANT;
  float* dinv  = wsf + OFF_DINV;
  float* ham0T = wsf + OFF_HAM0;
  float* ham1  = wsf + OFF_HAM1;
  float* wihT  = wsf + OFF_WIHT;
  float* whhT  = wsf + OFF_WHHT;
  __half* S1h   = (__half*)(wsf + OFF_S1H);
  __half* feath = (__half*)(wsf + OFF_FEATH);
  float* outp  = (float*)d_out;

  k_dinv  <<<NND, 64, 0, stream>>>(adj, dinv);
  k_anT   <<<(NND*NND + 255)/256, 256, 0, stream>>>(adj, dinv, anT);
  k_ham   <<<17, 256, 0, stream>>>(w0, w1, ham0T, ham1);
  k_wT    <<<(FSTR*192 + 64*192)/256, 256, 0, stream>>>(w_ih, w_hh, wihT, whhT);
  k_extras<<<(NND*BBATCH*LSEQ)/256, 256, 0, stream>>>(hist, tid_emb, dw_emb, feath);
  k_gemm1 <<<5*768, 256, 0, stream>>>(anT, hist, ham0T, ham1, bng, bnb, bnm, bnv, S1h);
  k_gemm2 <<<5*768, 256, 0, stream>>>(anT, S1h, bng, bnb, bnm, bnv, feath);
  k_gru   <<<NROWS/64, 256, 0, stream>>>(feath, wihT, whhT, b_ih, b_hh, fc_w, fc_b, outp);
}

// Round 3
// 868.281 us; speedup vs baseline: 1.8676x; 1.5146x over previous
//
#include <hip/hip_runtime.h>
#include <hip/hip_fp16.h>

// ---------------------------------------------------------------------------
// QGNN traffic predictor. R3: fp16 MFMA (16x16x32) for both graph-conv GEMMs.
// a_n stored fp16 [320][320] zero-padded; S1 stored transposed S1T[j][312].
// ---------------------------------------------------------------------------

#define NND 307
#define BBATCH 128
#define LSEQ 12
#define HIDN 64
#define JTOT (BBATCH*LSEQ*HIDN)   // 98304
#define FSTR 76
#define NROWS (NND*BBATCH)
#define KPAD 320                  // padded node dim for A / K-loop
#define MSTR 312                  // S1T row stride (f16), 16B-aligned, >=307

// workspace layout (float units)
#define OFF_DINV  0               // 320
#define OFF_HAM0  320             // ham0T [64][4] f32
#define OFF_HAM1  576             // ham1 [64][64] f32
#define OFF_WIHT  4672            // [76][192]
#define OFF_WHHT  19264           // [64][192]
#define OFF_ANNH  31552           // __half anN [320][320] = 51200 fl
#define OFF_S1T   82752           // __half S1T [98304][312] = 15335424 fl
#define OFF_FEATH 15418176        // __half feat [39296][12][76] = 17915904 fl
// total 33,334,080 floats = 127.2 MiB

typedef _Float16 half8 __attribute__((ext_vector_type(8)));
typedef float f32x4 __attribute__((ext_vector_type(4)));

__device__ __forceinline__ float sigmoidf_(float x){ return 1.f/(1.f+expf(-x)); }

// ---------------- adjacency normalization ----------------
__global__ void k_dinv(const float* __restrict__ adj, float* __restrict__ dinv){
  int n = blockIdx.x; int lane = threadIdx.x;
  float s = 0.f;
  for (int m = lane; m < NND; m += 64) s += adj[n*NND+m] + (m==n ? 1.f : 0.f);
  #pragma unroll
  for (int o = 32; o > 0; o >>= 1) s += __shfl_down(s, o);
  if (lane == 0) dinv[n] = 1.f/sqrtf(s);
}

// a_n as fp16, [320][320] zero-padded
__global__ void k_anN(const float* __restrict__ adj, const float* __restrict__ dinv,
                      __half* __restrict__ anN){
  int id = blockIdx.x*256 + threadIdx.x;
  if (id >= KPAD*KPAD) return;
  int n = id / KPAD, m = id % KPAD;
  float v = 0.f;
  if (n < NND && m < NND)
    v = dinv[n] * (adj[n*NND+m] + (n==m ? 1.f : 0.f)) * dinv[m];
  anN[id] = __float2half(v);
}

// ---------------- Hamilton matrices ----------------
__global__ void k_ham(const float* __restrict__ w0, const float* __restrict__ w1,
                      float* __restrict__ ham0T, float* __restrict__ ham1){
  const int  comp[4][4] = {{0,1,2,3},{1,0,3,2},{2,3,0,1},{3,2,1,0}};
  const float sgn[4][4] = {{1.f,1.f,1.f,1.f},{-1.f,1.f,1.f,-1.f},
                           {-1.f,-1.f,1.f,1.f},{-1.f,1.f,-1.f,1.f}};
  int id = blockIdx.x*256 + threadIdx.x;
  if (id < 64) {
    int d = id, qb = d>>4, cc = d&15;
    #pragma unroll
    for (int c = 0; c < 4; ++c)
      ham0T[d*4+c] = sgn[c][qb] * w0[comp[c][qb]*16 + cc];
  }
  int id1 = id - 256;
  if (id1 >= 0 && id1 < 4096) {
    int drow = id1 >> 6, d = id1 & 63;
    int pb = drow>>4, rr = drow&15, qb = d>>4, cc = d&15;
    ham1[id1] = sgn[pb][qb] * w1[rr*64 + comp[pb][qb]*16 + cc];
  }
}

// ---------------- GRU weight transpose ----------------
__global__ void k_wT(const float* __restrict__ w_ih, const float* __restrict__ w_hh,
                     float* __restrict__ wihT, float* __restrict__ whhT){
  int id = blockIdx.x*256 + threadIdx.x;
  if (id < FSTR*192) {
    int k = id / 192, g = id % 192;
    wihT[id] = (k < 75) ? w_ih[g*75 + k] : 0.f;
  } else {
    int id2 = id - FSTR*192;
    if (id2 < 64*192) {
      int k = id2 / 192, g = id2 % 192;
      whhT[id2] = w_hh[g*64 + k];
    }
  }
}

// ---------------- feat extras ----------------
__global__ void k_extras(const float* __restrict__ hist, const float* __restrict__ tid_emb,
                         const float* __restrict__ dw_emb, __half* __restrict__ feat){
  int id = blockIdx.x*256 + threadIdx.x;
  if (id >= NND*BBATCH*LSEQ) return;
  int n = id / (BBATCH*LSEQ); int rem = id % (BBATCH*LSEQ);
  int b = rem / LSEQ; int l = rem % LSEQ;
  const float* h = hist + ((size_t)(b*LSEQ + l)*NND + n)*4;
  float sp = h[0];
  int ti  = (int)rintf(h[1]*287.f);
  int dwi = (int)rintf(h[2]*6.f);
  __half* f = feat + ((size_t)(n*BBATCH + b)*LSEQ + l)*FSTR + 64;
  f[0] = __float2half(sp);
  #pragma unroll
  for (int c = 0; c < 5; ++c) f[1+c] = __float2half(tid_emb[ti*5+c]);
  #pragma unroll
  for (int c = 0; c < 5; ++c) f[6+c] = __float2half(dw_emb[dwi*5+c]);
  f[11] = __float2half(0.f);
}

// ---------------- GEMM1 (MFMA): X1 = a_n @ (hist x ham0); epi: BN0+tanh, @ham1 -> S1T
struct SG1 {
  union {
    struct { __half Af[64][40]; __half Bt[128][40]; float hs[2][2][32][4]; } m; // 17408B
    struct { float x1[64][132]; } e;                                            // 33792B
  } u;
  float ham1s[64][64];   // 16384B
  float sc[64], bi[64];  // 512B
};

__global__ __launch_bounds__(256) void k_gemm1(
    const __half* __restrict__ anN, const float* __restrict__ hist,
    const float* __restrict__ ham0Tg, const float* __restrict__ ham1g,
    const float* __restrict__ bng, const float* __restrict__ bnb,
    const float* __restrict__ bnm, const float* __restrict__ bnv,
    __half* __restrict__ S1T){
  __shared__ SG1 s;
  const int t = threadIdx.x;
  const int l = t & 63, wv = t >> 6;
  const int bidm = blockIdx.x / 768, bidj = blockIdx.x % 768;
  const int m0 = bidm*64, j0 = bidj*128;
  if (t < 64) {
    float sc = bng[t] / sqrtf(bnv[t] + 1e-5f);
    s.sc[t] = sc; s.bi[t] = bnb[t] - bnm[t]*sc;
  }
  for (int i = t; i < 4096; i += 256) (&s.ham1s[0][0])[i] = ham1g[i];

  // B-gen params: thread t -> row jj (0..127), k-half kh
  const int jj = t >> 1, kh = t & 1;
  const int dB = jj & 63;
  const float4 h0 = *(const float4*)(ham0Tg + dB*4);
  // A-stage params
  const int rA = t >> 2, cA = (t & 3)*8;
  // (b,l) for the two 64-col groups
  const int b0 = j0/768,      l0 = (j0/64)%12;
  const int b1 = (j0+64)/768, l1 = ((j0+64)/64)%12;
  const size_t hbase0 = ((size_t)(b0*LSEQ+l0)*NND)*4;
  const size_t hbase1 = ((size_t)(b1*LSEQ+l1)*NND)*4;
  // wave output tile: 32m x 64j
  const int moff = (wv>>1)*32, joff = (wv&1)*64;

  f32x4 acc[2][4];
  #pragma unroll
  for (int a=0;a<2;++a)
    #pragma unroll
    for (int b=0;b<4;++b) acc[a][b] = (f32x4){0.f,0.f,0.f,0.f};

  // prefetch hist chunk for ks=0
  if (t < 64) {
    int blh = t>>5, kkh = t&31;
    size_t hb = blh ? hbase1 : hbase0;
    *(float4*)&s.u.m.hs[0][blh][kkh][0] = *(const float4*)(hist + hb + (size_t)kkh*4);
  }
  __syncthreads();

  for (int ks = 0; ks < 10; ++ks) {
    const int k0 = ks*32, cur = ks & 1;
    // stage A tile (zero-padded global, branchless)
    *(uint4*)&s.u.m.Af[rA][cA] = *(const uint4*)(anN + (size_t)(m0+rA)*KPAD + k0 + cA);
    // generate B tile: Bt[jj][kk] = S0[k0+kk][j0+jj]
    {
      union { __half h[16]; uint4 v[2]; } tmp;
      #pragma unroll
      for (int i = 0; i < 16; ++i) {
        float4 h4 = *(const float4*)&s.u.m.hs[cur][jj>>6][kh*16+i][0];
        tmp.h[i] = __float2half(h4.x*h0.x + h4.y*h0.y + h4.z*h0.z + h4.w*h0.w);
      }
      *(uint4*)&s.u.m.Bt[jj][kh*16]   = tmp.v[0];
      *(uint4*)&s.u.m.Bt[jj][kh*16+8] = tmp.v[1];
    }
    __syncthreads();
    // prefetch next hist chunk
    if (ks < 9 && t < 64) {
      int blh = t>>5, kkh = t&31;
      int kg = (ks+1)*32 + kkh;
      size_t hb = blh ? hbase1 : hbase0;
      float4 h4 = make_float4(0.f,0.f,0.f,0.f);
      if (kg < NND) h4 = *(const float4*)(hist + hb + (size_t)kg*4);
      *(float4*)&s.u.m.hs[cur^1][blh][kkh][0] = h4;
    }
    // fragments + MFMA
    half8 a8[2], b8[4];
    #pragma unroll
    for (int mf = 0; mf < 2; ++mf)
      a8[mf] = *(const half8*)&s.u.m.Af[moff + mf*16 + (l&15)][(l>>4)*8];
    #pragma unroll
    for (int jf = 0; jf < 4; ++jf)
      b8[jf] = *(const half8*)&s.u.m.Bt[joff + jf*16 + (l&15)][(l>>4)*8];
    #pragma unroll
    for (int mf = 0; mf < 2; ++mf)
      #pragma unroll
      for (int jf = 0; jf < 4; ++jf)
        acc[mf][jf] = __builtin_amdgcn_mfma_f32_16x16x32_f16(a8[mf], b8[jf], acc[mf][jf], 0, 0, 0);
    __syncthreads();
  }

  // epilogue phase 1: BN0 + tanh -> x1[64][132] f32
  #pragma unroll
  for (int mf = 0; mf < 2; ++mf)
    #pragma unroll
    for (int jf = 0; jf < 4; ++jf)
      #pragma unroll
      for (int r = 0; r < 4; ++r) {
        int mm = moff + mf*16 + (l>>4)*4 + r;
        int jc = joff + jf*16 + (l&15);
        int d = jc & 63;
        s.u.e.x1[mm][jc] = tanhf(acc[mf][jf][r]*s.sc[d] + s.bi[d]);
      }
  __syncthreads();
  // epilogue phase 2: mini-GEMM over din=64 -> S1T
  const int tx = t & 31, ty = t >> 5;
  const int g64 = (tx >= 16) ? 64 : 0;
  const int dp = (tx & 15)*4;
  float e[8][4];
  #pragma unroll
  for (int r=0;r<8;++r)
    #pragma unroll
    for (int c=0;c<4;++c) e[r][c]=0.f;
  #pragma unroll 4
  for (int dd4 = 0; dd4 < 16; ++dd4) {
    float4 hb0 = *(const float4*)&s.ham1s[dd4*4+0][dp];
    float4 hb1 = *(const float4*)&s.ham1s[dd4*4+1][dp];
    float4 hb2 = *(const float4*)&s.ham1s[dd4*4+2][dp];
    float4 hb3 = *(const float4*)&s.ham1s[dd4*4+3][dp];
    #pragma unroll
    for (int r = 0; r < 8; ++r) {
      float4 xr = *(const float4*)&s.u.e.x1[ty*8+r][g64 + dd4*4];
      e[r][0] = fmaf(xr.x, hb0.x, fmaf(xr.y, hb1.x, fmaf(xr.z, hb2.x, fmaf(xr.w, hb3.x, e[r][0]))));
      e[r][1] = fmaf(xr.x, hb0.y, fmaf(xr.y, hb1.y, fmaf(xr.z, hb2.y, fmaf(xr.w, hb3.y, e[r][1]))));
      e[r][2] = fmaf(xr.x, hb0.z, fmaf(xr.y, hb1.z, fmaf(xr.z, hb2.z, fmaf(xr.w, hb3.z, e[r][2]))));
      e[r][3] = fmaf(xr.x, hb0.w, fmaf(xr.y, hb1.w, fmaf(xr.z, hb2.w, fmaf(xr.w, hb3.w, e[r][3]))));
    }
  }
  const int mbase = m0 + ty*8;
  if (mbase < MSTR) {
    #pragma unroll
    for (int c = 0; c < 4; ++c) {
      union { __half h[8]; uint4 v; } pk;
      #pragma unroll
      for (int r = 0; r < 8; ++r) pk.h[r] = __float2half(e[r][c]);
      int jout = j0 + g64 + dp + c;
      *(uint4*)(S1T + (size_t)jout*MSTR + mbase) = pk.v;
    }
  }
}

// ---------------- GEMM2 (MFMA): X2 = a_n @ S1; epi: BN1+tanh -> feat[:, :, 0:64]
struct SG2 {
  union {
    struct { __half Af[64][40]; __half Bt[128][40]; } m;  // 15360B
    struct { __half x2[64][2][72]; } e;                   // 18432B
  } u;
  float sc[64], bi[64];
};

__global__ __launch_bounds__(256) void k_gemm2(
    const __half* __restrict__ anN, const __half* __restrict__ S1T,
    const float* __restrict__ bng, const float* __restrict__ bnb,
    const float* __restrict__ bnm, const float* __restrict__ bnv,
    __half* __restrict__ feat){
  __shared__ SG2 s;
  const int t = threadIdx.x;
  const int l = t & 63, wv = t >> 6;
  const int bidm = blockIdx.x / 768, bidj = blockIdx.x % 768;
  const int m0 = bidm*64, j0 = bidj*128;
  if (t < 64) {
    float sc = bng[64+t] / sqrtf(bnv[64+t] + 1e-5f);
    s.sc[t] = sc; s.bi[t] = bnb[64+t] - bnm[64+t]*sc;
  }
  const int rA = t >> 2, cA = (t & 3)*8;
  const int jj = t >> 1, off = (t & 1)*16;
  const int moff = (wv>>1)*32, joff = (wv&1)*64;

  f32x4 acc[2][4];
  #pragma unroll
  for (int a=0;a<2;++a)
    #pragma unroll
    for (int b=0;b<4;++b) acc[a][b] = (f32x4){0.f,0.f,0.f,0.f};

  for (int ks = 0; ks < 10; ++ks) {
    const int k0 = ks*32;
    __syncthreads();
    *(uint4*)&s.u.m.Af[rA][cA] = *(const uint4*)(anN + (size_t)(m0+rA)*KPAD + k0 + cA);
    {
      const __half* src = S1T + (size_t)(j0+jj)*MSTR + k0 + off;
      uint4 v0 = *(const uint4*)src;
      uint4 v1 = *(const uint4*)(src + 8);
      *(uint4*)&s.u.m.Bt[jj][off]     = v0;
      *(uint4*)&s.u.m.Bt[jj][off + 8] = v1;
    }
    __syncthreads();
    half8 a8[2], b8[4];
    #pragma unroll
    for (int mf = 0; mf < 2; ++mf)
      a8[mf] = *(const half8*)&s.u.m.Af[moff + mf*16 + (l&15)][(l>>4)*8];
    #pragma unroll
    for (int jf = 0; jf < 4; ++jf)
      b8[jf] = *(const half8*)&s.u.m.Bt[joff + jf*16 + (l&15)][(l>>4)*8];
    #pragma unroll
    for (int mf = 0; mf < 2; ++mf)
      #pragma unroll
      for (int jf = 0; jf < 4; ++jf)
        acc[mf][jf] = __builtin_amdgcn_mfma_f32_16x16x32_f16(a8[mf], b8[jf], acc[mf][jf], 0, 0, 0);
  }
  __syncthreads();
  // BN1 + tanh -> x2[m][bl][d]
  #pragma unroll
  for (int mf = 0; mf < 2; ++mf)
    #pragma unroll
    for (int jf = 0; jf < 4; ++jf)
      #pragma unroll
      for (int r = 0; r < 4; ++r) {
        int mm = moff + mf*16 + (l>>4)*4 + r;
        int jc = joff + jf*16 + (l&15);
        int bl = jc >> 6, d = jc & 63;
        float v = tanhf(acc[mf][jf][r]*s.sc[d] + s.bi[d]);
        s.u.e.x2[mm][bl][d] = __float2half(v);
      }
  __syncthreads();
  // write out: 2 threads per (m,bl) row, 64B each, 8B stores
  {
    int pr = t >> 1, hf = t & 1;
    int mm = pr >> 1, bl = pr & 1;
    int n = m0 + mm;
    if (n < NND) {
      int jg = j0 + bl*64;
      int b = jg/768, lq = (jg/64)%12;
      __half* dst = feat + ((size_t)(n*BBATCH + b)*LSEQ + lq)*FSTR + hf*32;
      const __half* srcl = &s.u.e.x2[mm][bl][hf*32];
      #pragma unroll
      for (int i = 0; i < 8; ++i)
        *(uint2*)(dst + i*4) = *(const uint2*)(srcl + i*4);
    }
  }
}

// ---------------- GRU (12 steps) + ReLU + FC head ----------------
__global__ __launch_bounds__(256) void k_gru(
    const __half* __restrict__ feat, const float* __restrict__ wihT,
    const float* __restrict__ whhT, const float* __restrict__ b_ih,
    const float* __restrict__ b_hh, const float* __restrict__ fc_w,
    const float* __restrict__ fc_b, float* __restrict__ out){
  __shared__ float hT[64][64];
  __shared__ float red[4][64];
  const int lane = threadIdx.x & 63;
  const int wv = threadIdx.x >> 6;
  const int dbase = __builtin_amdgcn_readfirstlane(wv) * 16;
  const int row = blockIdx.x*64 + lane;
  for (int i = threadIdx.x; i < 64*64; i += 256) (&hT[0][0])[i] = 0.f;
  __syncthreads();
  const __half* xrow = feat + (size_t)row * (LSEQ*FSTR);

  for (int tstep = 0; tstep < 12; ++tstep) {
    float aR[16], aZ[16], aI[16], aH[16];
    #pragma unroll
    for (int i = 0; i < 16; ++i) { aR[i]=0.f; aZ[i]=0.f; aI[i]=0.f; aH[i]=0.f; }
    const __half2* xp = (const __half2*)(xrow + (size_t)tstep*FSTR);
    for (int kc = 0; kc < 19; ++kc) {
      float2 f0 = __half22float2(xp[2*kc]);
      float2 f1 = __half22float2(xp[2*kc+1]);
      float xs[4] = {f0.x, f0.y, f1.x, f1.y};
      #pragma unroll
      for (int kk = 0; kk < 4; ++kk) {
        const float* wr = wihT + (kc*4+kk)*192 + dbase;
        float xv = xs[kk];
        #pragma unroll
        for (int dl = 0; dl < 16; ++dl) {
          aR[dl] = fmaf(wr[dl],     xv, aR[dl]);
          aZ[dl] = fmaf(wr[64+dl],  xv, aZ[dl]);
          aI[dl] = fmaf(wr[128+dl], xv, aI[dl]);
        }
      }
    }
    for (int k = 0; k < 64; ++k) {
      float hv = hT[k][lane];
      const float* wr = whhT + k*192 + dbase;
      #pragma unroll
      for (int dl = 0; dl < 16; ++dl) {
        aR[dl] = fmaf(wr[dl],     hv, aR[dl]);
        aZ[dl] = fmaf(wr[64+dl],  hv, aZ[dl]);
        aH[dl] = fmaf(wr[128+dl], hv, aH[dl]);
      }
    }
    float hnew[16];
    #pragma unroll
    for (int dl = 0; dl < 16; ++dl) {
      int d = dbase + dl;
      float r  = sigmoidf_(aR[dl] + b_ih[d]     + b_hh[d]);
      float z  = sigmoidf_(aZ[dl] + b_ih[64+d]  + b_hh[64+d]);
      float nc = tanhf(aI[dl] + b_ih[128+d] + r*(aH[dl] + b_hh[128+d]));
      hnew[dl] = (1.f - z)*nc + z*hT[d][lane];
    }
    __syncthreads();
    #pragma unroll
    for (int dl = 0; dl < 16; ++dl) hT[dbase+dl][lane] = hnew[dl];
    __syncthreads();
    if (tstep >= 9) {
      float part = 0.f;
      #pragma unroll
      for (int dl = 0; dl < 16; ++dl)
        part = fmaf(fmaxf(hnew[dl], 0.f), fc_w[dbase+dl], part);
      red[wv][lane] = part;
      __syncthreads();
      if (wv == 0) {
        float sres = red[0][lane]+red[1][lane]+red[2][lane]+red[3][lane] + fc_b[0];
        int nn = row >> 7, bb = row & 127;
        out[(bb*3 + (tstep-9))*NND + nn] = sres;
      }
      __syncthreads();
    }
  }
}

// ---------------------------------------------------------------------------
extern "C" void kernel_launch(void* const* d_in, const int* in_sizes, int n_in,
                              void* d_out, int out_size, void* d_ws, size_t ws_size,
                              hipStream_t stream) {
  const float* hist    = (const float*)d_in[0];
  const float* adj     = (const float*)d_in[1];
  const float* w0      = (const float*)d_in[2];
  const float* w1      = (const float*)d_in[3];
  const float* bng     = (const float*)d_in[4];
  const float* bnb     = (const float*)d_in[5];
  const float* bnm     = (const float*)d_in[6];
  const float* bnv     = (const float*)d_in[7];
  const float* tid_emb = (const float*)d_in[8];
  const float* dw_emb  = (const float*)d_in[9];
  const float* w_ih    = (const float*)d_in[10];
  const float* w_hh    = (const float*)d_in[11];
  const float* b_ih    = (const float*)d_in[12];
  const float* b_hh    = (const float*)d_in[13];
  const float* fc_w    = (const float*)d_in[14];
  const float* fc_b    = (const float*)d_in[15];

  float* wsf   = (float*)d_ws;
  float* dinv  = wsf + OFF_DINV;
  float* ham0T = wsf + OFF_HAM0;
  float* ham1  = wsf + OFF_HAM1;
  float* wihT  = wsf + OFF_WIHT;
  float* whhT  = wsf + OFF_WHHT;
  __half* anN   = (__half*)(wsf + OFF_ANNH);
  __half* S1T   = (__half*)(wsf + OFF_S1T);
  __half* feath = (__half*)(wsf + OFF_FEATH);
  float* outp  = (float*)d_out;

  k_dinv  <<<NND, 64, 0, stream>>>(adj, dinv);
  k_anN   <<<(KPAD*KPAD + 255)/256, 256, 0, stream>>>(adj, dinv, anN);
  k_ham   <<<17, 256, 0, stream>>>(w0, w1, ham0T, ham1);
  k_wT    <<<(FSTR*192 + 64*192)/256, 256, 0, stream>>>(w_ih, w_hh, wihT, whhT);
  k_extras<<<(NND*BBATCH*LSEQ + 255)/256, 256, 0, stream>>>(hist, tid_emb, dw_emb, feath);
  k_gemm1 <<<5*768, 256, 0, stream>>>(anN, hist, ham0T, ham1, bng, bnb, bnm, bnv, S1T);
  k_gemm2 <<<5*768, 256, 0, stream>>>(anN, S1T, bng, bnb, bnm, bnv, feath);
  k_gru   <<<NROWS/64, 256, 0, stream>>>(feath, wihT, whhT, b_ih, b_hh, fc_w, fc_b, outp);
}

// Round 4
// 466.716 us; speedup vs baseline: 3.4745x; 1.8604x over previous
//
#include <hip/hip_runtime.h>
#include <hip/hip_fp16.h>

// ---------------------------------------------------------------------------
// QGNN traffic predictor. R4: MFMA GRU (both GEMVs), granule-interleaved LDS.
// ---------------------------------------------------------------------------

#define NND 307
#define BBATCH 128
#define LSEQ 12
#define HIDN 64
#define JTOT (BBATCH*LSEQ*HIDN)   // 98304
#define NROWS (NND*BBATCH)        // 39296
#define KPAD 320
#define MSTR 312                  // S1T row stride (halves)
#define F2S 80                    // feat2 row stride (halves)

// workspace layout (float units)
#define OFF_DINV  0
#define OFF_HAM0  320
#define OFF_HAM1  576
#define OFF_WIHP  4672            // __half [10][192][8] = 15360 h
#define OFF_WHHP  12352           // __half [8][192][8] = 12288 h
#define OFF_ANNH  18496           // __half anN [320][320]
#define OFF_S1T   69696           // __half S1T [98304][312]
#define OFF_FEATH 15405120        // __half feat2 [12][39296][80]
// end = 34,267,200 floats = 137.1 MB

typedef _Float16 half8 __attribute__((ext_vector_type(8)));
typedef float f32x4 __attribute__((ext_vector_type(4)));

// ---------------- adjacency normalization ----------------
__global__ void k_dinv(const float* __restrict__ adj, float* __restrict__ dinv){
  int n = blockIdx.x; int lane = threadIdx.x;
  float s = 0.f;
  for (int m = lane; m < NND; m += 64) s += adj[n*NND+m] + (m==n ? 1.f : 0.f);
  #pragma unroll
  for (int o = 32; o > 0; o >>= 1) s += __shfl_down(s, o);
  if (lane == 0) dinv[n] = 1.f/sqrtf(s);
}

__global__ void k_anN(const float* __restrict__ adj, const float* __restrict__ dinv,
                      __half* __restrict__ anN){
  int id = blockIdx.x*256 + threadIdx.x;
  if (id >= KPAD*KPAD) return;
  int n = id / KPAD, m = id % KPAD;
  float v = 0.f;
  if (n < NND && m < NND)
    v = dinv[n] * (adj[n*NND+m] + (n==m ? 1.f : 0.f)) * dinv[m];
  anN[id] = __float2half(v);
}

// ---------------- Hamilton matrices ----------------
__global__ void k_ham(const float* __restrict__ w0, const float* __restrict__ w1,
                      float* __restrict__ ham0T, float* __restrict__ ham1){
  const int  comp[4][4] = {{0,1,2,3},{1,0,3,2},{2,3,0,1},{3,2,1,0}};
  const float sgn[4][4] = {{1.f,1.f,1.f,1.f},{-1.f,1.f,1.f,-1.f},
                           {-1.f,-1.f,1.f,1.f},{-1.f,1.f,-1.f,1.f}};
  int id = blockIdx.x*256 + threadIdx.x;
  if (id < 64) {
    int d = id, qb = d>>4, cc = d&15;
    #pragma unroll
    for (int c = 0; c < 4; ++c)
      ham0T[d*4+c] = sgn[c][qb] * w0[comp[c][qb]*16 + cc];
  }
  int id1 = id - 256;
  if (id1 >= 0 && id1 < 4096) {
    int drow = id1 >> 6, d = id1 & 63;
    int pb = drow>>4, rr = drow&15, qb = d>>4, cc = d&15;
    ham1[id1] = sgn[pb][qb] * w1[rr*64 + comp[pb][qb]*16 + cc];
  }
}

// ---------------- GRU weight packing: [granule][col][8] fp16 ----------------
__global__ void k_wT(const float* __restrict__ w_ih, const float* __restrict__ w_hh,
                     __half* __restrict__ wihP, __half* __restrict__ whhP){
  int id = blockIdx.x*256 + threadIdx.x;
  if (id < 10*192*8) {
    int j = id & 7, col = (id >> 3) % 192, g = id / (192*8);
    int k = g*8 + j;
    wihP[id] = __float2half(k < 75 ? w_ih[col*75 + k] : 0.f);
  } else {
    int id2 = id - 10*192*8;
    if (id2 < 8*192*8) {
      int j = id2 & 7, col = (id2 >> 3) % 192, g = id2 / (192*8);
      whhP[id2] = __float2half(w_hh[col*64 + g*8 + j]);
    }
  }
}

// ---------------- feat extras: speed + embeddings into feat2 cols 64..79 ----
__global__ void k_extras(const float* __restrict__ hist, const float* __restrict__ tid_emb,
                         const float* __restrict__ dw_emb, __half* __restrict__ feat2){
  int id = blockIdx.x*256 + threadIdx.x;   // over LSEQ*NROWS
  if (id >= LSEQ*NROWS) return;
  int lq = id / NROWS, row = id % NROWS;
  int n = row >> 7, b = row & 127;
  const float* h = hist + ((size_t)(b*LSEQ + lq)*NND + n)*4;
  union { __half h16[16]; uint4 v[2]; } u;
  u.h16[0] = __float2half(h[0]);
  int ti  = (int)rintf(h[1]*287.f);
  int dwi = (int)rintf(h[2]*6.f);
  #pragma unroll
  for (int c = 0; c < 5; ++c) u.h16[1+c] = __float2half(tid_emb[ti*5+c]);
  #pragma unroll
  for (int c = 0; c < 5; ++c) u.h16[6+c] = __float2half(dw_emb[dwi*5+c]);
  #pragma unroll
  for (int c = 11; c < 16; ++c) u.h16[c] = __float2half(0.f);
  uint4* dst = (uint4*)(feat2 + (size_t)id*F2S + 64);
  dst[0] = u.v[0]; dst[1] = u.v[1];
}

// ---------------- GEMM1 (MFMA): X1 = a_n @ (hist x ham0); epi -> S1T --------
struct SG1 {
  union {
    struct { __half Af[64][40]; __half Bt[128][40]; float hs[2][2][32][4]; } m;
    struct { float x1[64][132]; } e;
  } u;
  float ham1s[64][64];
  float sc[64], bi[64];
};

__global__ __launch_bounds__(256) void k_gemm1(
    const __half* __restrict__ anN, const float* __restrict__ hist,
    const float* __restrict__ ham0Tg, const float* __restrict__ ham1g,
    const float* __restrict__ bng, const float* __restrict__ bnb,
    const float* __restrict__ bnm, const float* __restrict__ bnv,
    __half* __restrict__ S1T){
  __shared__ SG1 s;
  const int t = threadIdx.x;
  const int l = t & 63, wv = t >> 6;
  const int bidm = blockIdx.x / 768, bidj = blockIdx.x % 768;
  const int m0 = bidm*64, j0 = bidj*128;
  if (t < 64) {
    float sc = bng[t] / sqrtf(bnv[t] + 1e-5f);
    s.sc[t] = sc; s.bi[t] = bnb[t] - bnm[t]*sc;
  }
  for (int i = t; i < 4096; i += 256) (&s.ham1s[0][0])[i] = ham1g[i];

  const int jj = t >> 1, kh = t & 1;
  const int dB = jj & 63;
  const float4 h0 = *(const float4*)(ham0Tg + dB*4);
  const int rA = t >> 2, cA = (t & 3)*8;
  const int b0 = j0/768,      l0 = (j0/64)%12;
  const int b1 = (j0+64)/768, l1 = ((j0+64)/64)%12;
  const size_t hbase0 = ((size_t)(b0*LSEQ+l0)*NND)*4;
  const size_t hbase1 = ((size_t)(b1*LSEQ+l1)*NND)*4;
  const int moff = (wv>>1)*32, joff = (wv&1)*64;

  f32x4 acc[2][4];
  #pragma unroll
  for (int a=0;a<2;++a)
    #pragma unroll
    for (int b=0;b<4;++b) acc[a][b] = (f32x4){0.f,0.f,0.f,0.f};

  if (t < 64) {
    int blh = t>>5, kkh = t&31;
    size_t hb = blh ? hbase1 : hbase0;
    *(float4*)&s.u.m.hs[0][blh][kkh][0] = *(const float4*)(hist + hb + (size_t)kkh*4);
  }
  __syncthreads();

  for (int ks = 0; ks < 10; ++ks) {
    const int k0 = ks*32, cur = ks & 1;
    *(uint4*)&s.u.m.Af[rA][cA] = *(const uint4*)(anN + (size_t)(m0+rA)*KPAD + k0 + cA);
    {
      union { __half h[16]; uint4 v[2]; } tmp;
      #pragma unroll
      for (int i = 0; i < 16; ++i) {
        float4 h4 = *(const float4*)&s.u.m.hs[cur][jj>>6][kh*16+i][0];
        tmp.h[i] = __float2half(h4.x*h0.x + h4.y*h0.y + h4.z*h0.z + h4.w*h0.w);
      }
      *(uint4*)&s.u.m.Bt[jj][kh*16]   = tmp.v[0];
      *(uint4*)&s.u.m.Bt[jj][kh*16+8] = tmp.v[1];
    }
    __syncthreads();
    if (ks < 9 && t < 64) {
      int blh = t>>5, kkh = t&31;
      int kg = (ks+1)*32 + kkh;
      size_t hb = blh ? hbase1 : hbase0;
      float4 h4 = make_float4(0.f,0.f,0.f,0.f);
      if (kg < NND) h4 = *(const float4*)(hist + hb + (size_t)kg*4);
      *(float4*)&s.u.m.hs[cur^1][blh][kkh][0] = h4;
    }
    half8 a8[2], b8[4];
    #pragma unroll
    for (int mf = 0; mf < 2; ++mf)
      a8[mf] = *(const half8*)&s.u.m.Af[moff + mf*16 + (l&15)][(l>>4)*8];
    #pragma unroll
    for (int jf = 0; jf < 4; ++jf)
      b8[jf] = *(const half8*)&s.u.m.Bt[joff + jf*16 + (l&15)][(l>>4)*8];
    #pragma unroll
    for (int mf = 0; mf < 2; ++mf)
      #pragma unroll
      for (int jf = 0; jf < 4; ++jf)
        acc[mf][jf] = __builtin_amdgcn_mfma_f32_16x16x32_f16(a8[mf], b8[jf], acc[mf][jf], 0, 0, 0);
    __syncthreads();
  }

  #pragma unroll
  for (int mf = 0; mf < 2; ++mf)
    #pragma unroll
    for (int jf = 0; jf < 4; ++jf)
      #pragma unroll
      for (int r = 0; r < 4; ++r) {
        int mm = moff + mf*16 + (l>>4)*4 + r;
        int jc = joff + jf*16 + (l&15);
        int d = jc & 63;
        s.u.e.x1[mm][jc] = tanhf(acc[mf][jf][r]*s.sc[d] + s.bi[d]);
      }
  __syncthreads();
  const int tx = t & 31, ty = t >> 5;
  const int g64 = (tx >= 16) ? 64 : 0;
  const int dp = (tx & 15)*4;
  float e[8][4];
  #pragma unroll
  for (int r=0;r<8;++r)
    #pragma unroll
    for (int c=0;c<4;++c) e[r][c]=0.f;
  #pragma unroll 4
  for (int dd4 = 0; dd4 < 16; ++dd4) {
    float4 hb0 = *(const float4*)&s.ham1s[dd4*4+0][dp];
    float4 hb1 = *(const float4*)&s.ham1s[dd4*4+1][dp];
    float4 hb2 = *(const float4*)&s.ham1s[dd4*4+2][dp];
    float4 hb3 = *(const float4*)&s.ham1s[dd4*4+3][dp];
    #pragma unroll
    for (int r = 0; r < 8; ++r) {
      float4 xr = *(const float4*)&s.u.e.x1[ty*8+r][g64 + dd4*4];
      e[r][0] = fmaf(xr.x, hb0.x, fmaf(xr.y, hb1.x, fmaf(xr.z, hb2.x, fmaf(xr.w, hb3.x, e[r][0]))));
      e[r][1] = fmaf(xr.x, hb0.y, fmaf(xr.y, hb1.y, fmaf(xr.z, hb2.y, fmaf(xr.w, hb3.y, e[r][1]))));
      e[r][2] = fmaf(xr.x, hb0.z, fmaf(xr.y, hb1.z, fmaf(xr.z, hb2.z, fmaf(xr.w, hb3.z, e[r][2]))));
      e[r][3] = fmaf(xr.x, hb0.w, fmaf(xr.y, hb1.w, fmaf(xr.z, hb2.w, fmaf(xr.w, hb3.w, e[r][3]))));
    }
  }
  const int mbase = m0 + ty*8;
  if (mbase < MSTR) {
    #pragma unroll
    for (int c = 0; c < 4; ++c) {
      union { __half h[8]; uint4 v; } pk;
      #pragma unroll
      for (int r = 0; r < 8; ++r) pk.h[r] = __float2half(e[r][c]);
      int jout = j0 + g64 + dp + c;
      *(uint4*)(S1T + (size_t)jout*MSTR + mbase) = pk.v;
    }
  }
}

// ---------------- GEMM2 (MFMA): X2 = a_n @ S1; epi: BN1+tanh -> feat2 -------
struct SG2 {
  union {
    struct { __half Af[64][40]; __half Bt[128][40]; } m;
    struct { __half x2[64][2][72]; } e;
  } u;
  float sc[64], bi[64];
};

__global__ __launch_bounds__(256) void k_gemm2(
    const __half* __restrict__ anN, const __half* __restrict__ S1T,
    const float* __restrict__ bng, const float* __restrict__ bnb,
    const float* __restrict__ bnm, const float* __restrict__ bnv,
    __half* __restrict__ feat2){
  __shared__ SG2 s;
  const int t = threadIdx.x;
  const int l = t & 63, wv = t >> 6;
  const int bidm = blockIdx.x / 768, bidj = blockIdx.x % 768;
  const int m0 = bidm*64, j0 = bidj*128;
  if (t < 64) {
    float sc = bng[64+t] / sqrtf(bnv[64+t] + 1e-5f);
    s.sc[t] = sc; s.bi[t] = bnb[64+t] - bnm[64+t]*sc;
  }
  const int rA = t >> 2, cA = (t & 3)*8;
  const int jj = t >> 1, off = (t & 1)*16;
  const int moff = (wv>>1)*32, joff = (wv&1)*64;

  f32x4 acc[2][4];
  #pragma unroll
  for (int a=0;a<2;++a)
    #pragma unroll
    for (int b=0;b<4;++b) acc[a][b] = (f32x4){0.f,0.f,0.f,0.f};

  for (int ks = 0; ks < 10; ++ks) {
    const int k0 = ks*32;
    __syncthreads();
    *(uint4*)&s.u.m.Af[rA][cA] = *(const uint4*)(anN + (size_t)(m0+rA)*KPAD + k0 + cA);
    {
      const __half* src = S1T + (size_t)(j0+jj)*MSTR + k0 + off;
      uint4 v0 = *(const uint4*)src;
      uint4 v1 = *(const uint4*)(src + 8);
      *(uint4*)&s.u.m.Bt[jj][off]     = v0;
      *(uint4*)&s.u.m.Bt[jj][off + 8] = v1;
    }
    __syncthreads();
    half8 a8[2], b8[4];
    #pragma unroll
    for (int mf = 0; mf < 2; ++mf)
      a8[mf] = *(const half8*)&s.u.m.Af[moff + mf*16 + (l&15)][(l>>4)*8];
    #pragma unroll
    for (int jf = 0; jf < 4; ++jf)
      b8[jf] = *(const half8*)&s.u.m.Bt[joff + jf*16 + (l&15)][(l>>4)*8];
    #pragma unroll
    for (int mf = 0; mf < 2; ++mf)
      #pragma unroll
      for (int jf = 0; jf < 4; ++jf)
        acc[mf][jf] = __builtin_amdgcn_mfma_f32_16x16x32_f16(a8[mf], b8[jf], acc[mf][jf], 0, 0, 0);
  }
  __syncthreads();
  #pragma unroll
  for (int mf = 0; mf < 2; ++mf)
    #pragma unroll
    for (int jf = 0; jf < 4; ++jf)
      #pragma unroll
      for (int r = 0; r < 4; ++r) {
        int mm = moff + mf*16 + (l>>4)*4 + r;
        int jc = joff + jf*16 + (l&15);
        int bl = jc >> 6, d = jc & 63;
        float v = tanhf(acc[mf][jf][r]*s.sc[d] + s.bi[d]);
        s.u.e.x2[mm][bl][d] = __float2half(v);
      }
  __syncthreads();
  {
    int pr = t >> 1, hf = t & 1;
    int mm = pr >> 1, bl = pr & 1;
    int n = m0 + mm;
    if (n < NND) {
      int jg = j0 + bl*64;
      int b = jg/768, lq = (jg/64)%12;
      __half* dst = feat2 + ((size_t)lq*NROWS + n*BBATCH + b)*F2S + hf*32;
      const __half* srcl = &s.u.e.x2[mm][bl][hf*32];
      #pragma unroll
      for (int i = 0; i < 4; ++i)
        *(uint4*)(dst + i*8) = *(const uint4*)(srcl + i*8);
    }
  }
}

// ---------------- GRU (MFMA, 12 steps) + ReLU + FC head ---------------------
// 512 thr = 8 waves; 64 rows/block. wave (mt, ng): M-tile mt, d-half ng.
__global__ __launch_bounds__(512, 2) void k_gru(
    const __half* __restrict__ feat2, const __half* __restrict__ wihP,
    const __half* __restrict__ whhP, const float* __restrict__ b_ih,
    const float* __restrict__ b_hh, const float* __restrict__ fc_w,
    const float* __restrict__ fc_b, float* __restrict__ out){
  __shared__ __half wih[10*192*8];   // [g][col][8]
  __shared__ __half whh[8*192*8];
  __shared__ __half xt[10*64*8];     // [g][row][8]
  __shared__ __half Hs[8*64*8];
  __shared__ __half zst[16];
  __shared__ float red[4][2][16];

  const int t = threadIdx.x;
  const int l = t & 63, wv = t >> 6;
  const int mt = wv >> 1, ng = wv & 1;
  const int row0 = blockIdx.x * 64;

  for (int i = t; i < 10*192; i += 512) ((uint4*)wih)[i] = ((const uint4*)wihP)[i];
  for (int i = t; i < 8*192; i += 512)  ((uint4*)whh)[i] = ((const uint4*)whhP)[i];
  for (int i = t; i < 8*64; i += 512)   ((uint4*)Hs)[i] = make_uint4(0,0,0,0);
  if (t < 2) ((uint4*)zst)[t] = make_uint4(0,0,0,0);

  float bR[2], bZ[2], bI[2], bH[2], fw[2];
  #pragma unroll
  for (int s2 = 0; s2 < 2; ++s2) {
    int d = ng*32 + s2*16 + (l & 15);
    bR[s2] = b_ih[d]     + b_hh[d];
    bZ[s2] = b_ih[64+d]  + b_hh[64+d];
    bI[s2] = b_ih[128+d];
    bH[s2] = b_hh[128+d];
    fw[s2] = fc_w[d];
  }
  const float fcb = fc_b[0];
  float hreg[8];
  #pragma unroll
  for (int i = 0; i < 8; ++i) hreg[i] = 0.f;

  const int rst = t >> 3, qst = t & 7;  // staging map
  {
    const __half* src = feat2 + ((size_t)(row0 + rst))*F2S;
    *(uint4*)&xt[(qst*64 + rst)*8] = *(const uint4*)(src + qst*8);
    if (qst < 2) *(uint4*)&xt[((qst+8)*64 + rst)*8] = *(const uint4*)(src + (qst+8)*8);
  }
  __syncthreads();

  const int rowA = mt*16 + (l & 15);
  const int gq = l >> 4;
  const int colb = l & 15;
  const __half* axt0 = &xt[((0+gq)*64 + rowA)*8];
  const __half* axt1 = &xt[((4+gq)*64 + rowA)*8];
  const __half* axt2 = (gq < 2) ? &xt[((8+gq)*64 + rowA)*8] : zst;
  const __half* ah0  = &Hs[((0+gq)*64 + rowA)*8];
  const __half* ah1  = &Hs[((4+gq)*64 + rowA)*8];
  const __half* bi0  = &wih[((0+gq)*192 + colb)*8];
  const __half* bi1  = &wih[((4+gq)*192 + colb)*8];
  const __half* bi2  = (gq < 2) ? &wih[((8+gq)*192 + colb)*8] : zst;
  const int ntm2 = (gq < 2) ? 128 : 0;
  const __half* bh0  = &whh[((0+gq)*192 + colb)*8];
  const __half* bh1  = &whh[((4+gq)*192 + colb)*8];

  for (int ts = 0; ts < 12; ++ts) {
    half8 agi0 = *(const half8*)axt0;
    half8 agi1 = *(const half8*)axt1;
    half8 agi2 = *(const half8*)axt2;
    half8 agh0 = *(const half8*)ah0;
    half8 agh1 = *(const half8*)ah1;
    f32x4 aR[2], aZ[2], aIn[2], aHn[2];
    #pragma unroll
    for (int s2 = 0; s2 < 2; ++s2) {
      aR[s2] = (f32x4){0.f,0.f,0.f,0.f}; aZ[s2] = (f32x4){0.f,0.f,0.f,0.f};
      aIn[s2] = (f32x4){0.f,0.f,0.f,0.f}; aHn[s2] = (f32x4){0.f,0.f,0.f,0.f};
    }
    #pragma unroll
    for (int s2 = 0; s2 < 2; ++s2) {
      const int ntr = ng*2 + s2, ntz = 4 + ng*2 + s2, ntn = 8 + ng*2 + s2;
      aR[s2] = __builtin_amdgcn_mfma_f32_16x16x32_f16(agi0, *(const half8*)(bi0 + ntr*128), aR[s2], 0,0,0);
      aR[s2] = __builtin_amdgcn_mfma_f32_16x16x32_f16(agi1, *(const half8*)(bi1 + ntr*128), aR[s2], 0,0,0);
      aR[s2] = __builtin_amdgcn_mfma_f32_16x16x32_f16(agi2, *(const half8*)(bi2 + ntr*ntm2), aR[s2], 0,0,0);
      aR[s2] = __builtin_amdgcn_mfma_f32_16x16x32_f16(agh0, *(const half8*)(bh0 + ntr*128), aR[s2], 0,0,0);
      aR[s2] = __builtin_amdgcn_mfma_f32_16x16x32_f16(agh1, *(const half8*)(bh1 + ntr*128), aR[s2], 0,0,0);
      aZ[s2] = __builtin_amdgcn_mfma_f32_16x16x32_f16(agi0, *(const half8*)(bi0 + ntz*128), aZ[s2], 0,0,0);
      aZ[s2] = __builtin_amdgcn_mfma_f32_16x16x32_f16(agi1, *(const half8*)(bi1 + ntz*128), aZ[s2], 0,0,0);
      aZ[s2] = __builtin_amdgcn_mfma_f32_16x16x32_f16(agi2, *(const half8*)(bi2 + ntz*ntm2), aZ[s2], 0,0,0);
      aZ[s2] = __builtin_amdgcn_mfma_f32_16x16x32_f16(agh0, *(const half8*)(bh0 + ntz*128), aZ[s2], 0,0,0);
      aZ[s2] = __builtin_amdgcn_mfma_f32_16x16x32_f16(agh1, *(const half8*)(bh1 + ntz*128), aZ[s2], 0,0,0);
      aIn[s2] = __builtin_amdgcn_mfma_f32_16x16x32_f16(agi0, *(const half8*)(bi0 + ntn*128), aIn[s2], 0,0,0);
      aIn[s2] = __builtin_amdgcn_mfma_f32_16x16x32_f16(agi1, *(const half8*)(bi1 + ntn*128), aIn[s2], 0,0,0);
      aIn[s2] = __builtin_amdgcn_mfma_f32_16x16x32_f16(agi2, *(const half8*)(bi2 + ntn*ntm2), aIn[s2], 0,0,0);
      aHn[s2] = __builtin_amdgcn_mfma_f32_16x16x32_f16(agh0, *(const half8*)(bh0 + ntn*128), aHn[s2], 0,0,0);
      aHn[s2] = __builtin_amdgcn_mfma_f32_16x16x32_f16(agh1, *(const half8*)(bh1 + ntn*128), aHn[s2], 0,0,0);
    }
    float hnew[8];
    #pragma unroll
    for (int s2 = 0; s2 < 2; ++s2)
      #pragma unroll
      for (int rg = 0; rg < 4; ++rg) {
        const int i = s2*4 + rg;
        float pr = aR[s2][rg] + bR[s2];
        float pz = aZ[s2][rg] + bZ[s2];
        float pn = aIn[s2][rg] + bI[s2];
        float ph = aHn[s2][rg] + bH[s2];
        float r = 1.f / (1.f + exp2f(-1.44269504f * pr));
        float z = 1.f / (1.f + exp2f(-1.44269504f * pz));
        float e2 = exp2f(2.88539008f * (pn + r*ph));
        float nc = 1.f - 2.f/(e2 + 1.f);
        hnew[i] = (1.f - z)*nc + z*hreg[i];
        hreg[i] = hnew[i];
      }
    if (ts >= 9) {
      #pragma unroll
      for (int rg = 0; rg < 4; ++rg) {
        float p = fmaxf(hnew[rg],0.f)*fw[0] + fmaxf(hnew[4+rg],0.f)*fw[1];
        p += __shfl_xor(p, 1); p += __shfl_xor(p, 2);
        p += __shfl_xor(p, 4); p += __shfl_xor(p, 8);
        if (colb == 0) red[mt][ng][gq*4 + rg] = p;
      }
    }
    __syncthreads();   // (A) reads done; red visible
    if (ts >= 9 && ng == 0 && colb == 0) {
      #pragma unroll
      for (int rg = 0; rg < 4; ++rg) {
        int rr = gq*4 + rg;
        float sum = red[mt][0][rr] + red[mt][1][rr] + fcb;
        int grow = row0 + mt*16 + rr;
        out[((grow & 127)*3 + (ts-9))*NND + (grow >> 7)] = sum;
      }
    }
    if (ts < 11) {
      #pragma unroll
      for (int s2 = 0; s2 < 2; ++s2) {
        const int d = ng*32 + s2*16 + colb;
        #pragma unroll
        for (int rg = 0; rg < 4; ++rg) {
          int rw = mt*16 + gq*4 + rg;
          Hs[((d>>3)*64 + rw)*8 + (d&7)] = __float2half(hnew[s2*4+rg]);
        }
      }
      const __half* src = feat2 + ((size_t)(ts+1)*NROWS + row0 + rst)*F2S;
      *(uint4*)&xt[(qst*64 + rst)*8] = *(const uint4*)(src + qst*8);
      if (qst < 2) *(uint4*)&xt[((qst+8)*64 + rst)*8] = *(const uint4*)(src + (qst+8)*8);
    }
    __syncthreads();   // (B) writes visible
  }
}

// ---------------------------------------------------------------------------
extern "C" void kernel_launch(void* const* d_in, const int* in_sizes, int n_in,
                              void* d_out, int out_size, void* d_ws, size_t ws_size,
                              hipStream_t stream) {
  const float* hist    = (const float*)d_in[0];
  const float* adj     = (const float*)d_in[1];
  const float* w0      = (const float*)d_in[2];
  const float* w1      = (const float*)d_in[3];
  const float* bng     = (const float*)d_in[4];
  const float* bnb     = (const float*)d_in[5];
  const float* bnm     = (const float*)d_in[6];
  const float* bnv     = (const float*)d_in[7];
  const float* tid_emb = (const float*)d_in[8];
  const float* dw_emb  = (const float*)d_in[9];
  const float* w_ih    = (const float*)d_in[10];
  const float* w_hh    = (const float*)d_in[11];
  const float* b_ih    = (const float*)d_in[12];
  const float* b_hh    = (const float*)d_in[13];
  const float* fc_w    = (const float*)d_in[14];
  const float* fc_b    = (const float*)d_in[15];

  float* wsf   = (float*)d_ws;
  float* dinv  = wsf + OFF_DINV;
  float* ham0T = wsf + OFF_HAM0;
  float* ham1  = wsf + OFF_HAM1;
  __half* wihP  = (__half*)(wsf + OFF_WIHP);
  __half* whhP  = (__half*)(wsf + OFF_WHHP);
  __half* anN   = (__half*)(wsf + OFF_ANNH);
  __half* S1T   = (__half*)(wsf + OFF_S1T);
  __half* feat2 = (__half*)(wsf + OFF_FEATH);
  float* outp  = (float*)d_out;

  k_dinv  <<<NND, 64, 0, stream>>>(adj, dinv);
  k_anN   <<<(KPAD*KPAD + 255)/256, 256, 0, stream>>>(adj, dinv, anN);
  k_ham   <<<17, 256, 0, stream>>>(w0, w1, ham0T, ham1);
  k_wT    <<<108, 256, 0, stream>>>(w_ih, w_hh, wihP, whhP);
  k_extras<<<(LSEQ*NROWS + 255)/256, 256, 0, stream>>>(hist, tid_emb, dw_emb, feat2);
  k_gemm1 <<<5*768, 256, 0, stream>>>(anN, hist, ham0T, ham1, bng, bnb, bnm, bnv, S1T);
  k_gemm2 <<<5*768, 256, 0, stream>>>(anN, S1T, bng, bnb, bnm, bnv, feat2);
  k_gru   <<<NROWS/64, 512, 0, stream>>>(feat2, wihP, whhP, b_ih, b_hh, fc_w, fc_b, outp);
}

// Round 5
// 420.803 us; speedup vs baseline: 3.8536x; 1.1091x over previous
//
#include <hip/hip_runtime.h>
#include <hip/hip_fp16.h>

// ---------------------------------------------------------------------------
// QGNN traffic predictor. R5: S0 precomputed (k_s0); both GEMMs use
// granule-interleaved LDS tiles [g][row][8] (bank-conflict-free, GRU-proven).
// ---------------------------------------------------------------------------

#define NND 307
#define BBATCH 128
#define LSEQ 12
#define HIDN 64
#define JTOT (BBATCH*LSEQ*HIDN)   // 98304
#define NROWS (NND*BBATCH)        // 39296
#define KPAD 320
#define MSTR 312                  // S0T/S1T row stride (halves)
#define F2S 80                    // feat2 row stride (halves)

// workspace layout (float units)
#define OFF_DINV  0
#define OFF_HAM0  320
#define OFF_HAM1  576
#define OFF_WIHP  4672            // __half [10][192][8]
#define OFF_WHHP  12352           // __half [8][192][8]
#define OFF_ANG   18496           // __half anG [10][4][320][8] = 51200 fl
#define OFF_S1T   69696           // __half S1T [98304][312] = 15335424 fl
#define OFF_S0T   15405120        // __half S0T [98304][312]  (aliases feat2)
#define OFF_FEATH 15405120        // __half feat2 [12][39296][80] = 18862080 fl
// end = 34,267,200 floats = 137.1 MB (same as R4)

typedef _Float16 half8 __attribute__((ext_vector_type(8)));
typedef float f32x4 __attribute__((ext_vector_type(4)));

// ---------------- adjacency normalization ----------------
__global__ void k_dinv(const float* __restrict__ adj, float* __restrict__ dinv){
  int n = blockIdx.x; int lane = threadIdx.x;
  float s = 0.f;
  for (int m = lane; m < NND; m += 64) s += adj[n*NND+m] + (m==n ? 1.f : 0.f);
  #pragma unroll
  for (int o = 32; o > 0; o >>= 1) s += __shfl_down(s, o);
  if (lane == 0) dinv[n] = 1.f/sqrtf(s);
}

// a_n fp16, granule-tiled: anG[((ks*4+g)*320 + row)*8 + j] = a_n[row][ks*32+g*8+j]
__global__ void k_anG(const float* __restrict__ adj, const float* __restrict__ dinv,
                      __half* __restrict__ anG){
  int id = blockIdx.x*256 + threadIdx.x;
  if (id >= KPAD*KPAD) return;
  int n = id / KPAD, m = id % KPAD;
  float v = 0.f;
  if (n < NND && m < NND)
    v = dinv[n] * (adj[n*NND+m] + (n==m ? 1.f : 0.f)) * dinv[m];
  int ks = m >> 5, g = (m >> 3) & 3, j = m & 7;
  anG[(((ks*4 + g)*320 + n) << 3) + j] = __float2half(v);
}

// ---------------- Hamilton matrices ----------------
__global__ void k_ham(const float* __restrict__ w0, const float* __restrict__ w1,
                      float* __restrict__ ham0T, float* __restrict__ ham1){
  const int  comp[4][4] = {{0,1,2,3},{1,0,3,2},{2,3,0,1},{3,2,1,0}};
  const float sgn[4][4] = {{1.f,1.f,1.f,1.f},{-1.f,1.f,1.f,-1.f},
                           {-1.f,-1.f,1.f,1.f},{-1.f,1.f,-1.f,1.f}};
  int id = blockIdx.x*256 + threadIdx.x;
  if (id < 64) {
    int d = id, qb = d>>4, cc = d&15;
    #pragma unroll
    for (int c = 0; c < 4; ++c)
      ham0T[d*4+c] = sgn[c][qb] * w0[comp[c][qb]*16 + cc];
  }
  int id1 = id - 256;
  if (id1 >= 0 && id1 < 4096) {
    int drow = id1 >> 6, d = id1 & 63;
    int pb = drow>>4, rr = drow&15, qb = d>>4, cc = d&15;
    ham1[id1] = sgn[pb][qb] * w1[rr*64 + comp[pb][qb]*16 + cc];
  }
}

// ---------------- GRU weight packing: [granule][col][8] fp16 ----------------
__global__ void k_wT(const float* __restrict__ w_ih, const float* __restrict__ w_hh,
                     __half* __restrict__ wihP, __half* __restrict__ whhP){
  int id = blockIdx.x*256 + threadIdx.x;
  if (id < 10*192*8) {
    int j = id & 7, col = (id >> 3) % 192, g = id / (192*8);
    int k = g*8 + j;
    wihP[id] = __float2half(k < 75 ? w_ih[col*75 + k] : 0.f);
  } else {
    int id2 = id - 10*192*8;
    if (id2 < 8*192*8) {
      int j = id2 & 7, col = (id2 >> 3) % 192, g = id2 / (192*8);
      whhP[id2] = __float2half(w_hh[col*64 + g*8 + j]);
    }
  }
}

// ---------------- S0T = (hist x ham0)^T : [j=(b,l,d)][k] fp16 ---------------
__global__ __launch_bounds__(256) void k_s0(const float* __restrict__ hist,
                                            const float* __restrict__ ham0Tg,
                                            __half* __restrict__ S0T){
  __shared__ float4 histL[320];
  const int t = threadIdx.x;
  const int bl = blockIdx.x;             // b*12 + l
  for (int k = t; k < 320; k += 256)
    histL[k] = (k < NND) ? *(const float4*)(hist + ((size_t)bl*NND + k)*4)
                         : make_float4(0.f,0.f,0.f,0.f);
  __syncthreads();
  if (t < 154) {
    const int k0 = 2*t;
    const float4 hA = histL[k0], hB = histL[k0+1];
    const size_t jb = (size_t)bl*64;
    for (int d = 0; d < 64; ++d) {
      float4 h0 = *(const float4*)(ham0Tg + d*4);   // uniform -> s_load
      float vA = hA.x*h0.x + hA.y*h0.y + hA.z*h0.z + hA.w*h0.w;
      float vB = hB.x*h0.x + hB.y*h0.y + hB.z*h0.z + hB.w*h0.w;
      __half2 p = __floats2half2_rn(vA, vB);
      if (k0 + 1 < NND) *(__half2*)(S0T + (jb + d)*MSTR + k0) = p;
      else              S0T[(jb + d)*MSTR + k0] = __low2half(p);
    }
  }
}

// ---------------- feat extras: speed + embeddings into feat2 cols 64..79 ----
__global__ void k_extras(const float* __restrict__ hist, const float* __restrict__ tid_emb,
                         const float* __restrict__ dw_emb, __half* __restrict__ feat2){
  int id = blockIdx.x*256 + threadIdx.x;   // over LSEQ*NROWS
  if (id >= LSEQ*NROWS) return;
  int lq = id / NROWS, row = id % NROWS;
  int n = row >> 7, b = row & 127;
  const float* h = hist + ((size_t)(b*LSEQ + lq)*NND + n)*4;
  union { __half h16[16]; uint4 v[2]; } u;
  u.h16[0] = __float2half(h[0]);
  int ti  = (int)rintf(h[1]*287.f);
  int dwi = (int)rintf(h[2]*6.f);
  #pragma unroll
  for (int c = 0; c < 5; ++c) u.h16[1+c] = __float2half(tid_emb[ti*5+c]);
  #pragma unroll
  for (int c = 0; c < 5; ++c) u.h16[6+c] = __float2half(dw_emb[dwi*5+c]);
  #pragma unroll
  for (int c = 11; c < 16; ++c) u.h16[c] = __float2half(0.f);
  uint4* dst = (uint4*)(feat2 + (size_t)id*F2S + 64);
  dst[0] = u.v[0]; dst[1] = u.v[1];
}

// ---------------- GEMM1 (MFMA): X1 = a_n @ S0; epi: BN0+tanh, @ham1 -> S1T --
struct SG1 {
  union {
    struct { __half A[4][64][8]; __half B[4][128][8]; } m;   // 12KB
    struct { float x1[64][132]; } e;                         // 33792B
  } u;
  float ham1s[64][64];
  float sc[64], bi[64];
};

__global__ __launch_bounds__(256) void k_gemm1(
    const __half* __restrict__ anG, const __half* __restrict__ S0T,
    const float* __restrict__ ham1g,
    const float* __restrict__ bng, const float* __restrict__ bnb,
    const float* __restrict__ bnm, const float* __restrict__ bnv,
    __half* __restrict__ S1T){
  __shared__ SG1 s;
  const int t = threadIdx.x;
  const int l = t & 63, wv = t >> 6;
  const int bidm = blockIdx.x / 768, bidj = blockIdx.x % 768;
  const int m0 = bidm*64, j0 = bidj*128;
  if (t < 64) {
    float sc = bng[t] / sqrtf(bnv[t] + 1e-5f);
    s.sc[t] = sc; s.bi[t] = bnb[t] - bnm[t]*sc;
  }
  for (int i = t; i < 4096; i += 256) (&s.ham1s[0][0])[i] = ham1g[i];

  const int jB = t >> 1, hB = t & 1;      // B staging: row jB, k-half hB
  const int moff = (wv>>1)*32, joff = (wv&1)*64;

  f32x4 acc[2][4];
  #pragma unroll
  for (int a=0;a<2;++a)
    #pragma unroll
    for (int b=0;b<4;++b) acc[a][b] = (f32x4){0.f,0.f,0.f,0.f};

  for (int ks = 0; ks < 10; ++ks) {
    const int k0 = ks*32;
    // A: wave wv stages granule wv, row l (coalesced global, stride-1 LDS)
    uint4 av = *(const uint4*)(anG + ((((ks*4 + wv)*320) + m0 + l) << 3));
    // B: thread stages 32B of S0T row jB -> granules hB*2, hB*2+1
    const __half* bsrc = S0T + (size_t)(j0 + jB)*MSTR + k0 + hB*16;
    uint4 b0 = *(const uint4*)bsrc;
    uint4 b1 = *(const uint4*)(bsrc + 8);
    *(uint4*)&s.u.m.A[wv][l][0]        = av;
    *(uint4*)&s.u.m.B[hB*2][jB][0]     = b0;
    *(uint4*)&s.u.m.B[hB*2+1][jB][0]   = b1;
    __syncthreads();
    half8 a8[2], b8[4];
    #pragma unroll
    for (int mf = 0; mf < 2; ++mf)
      a8[mf] = *(const half8*)&s.u.m.A[l>>4][moff + mf*16 + (l&15)][0];
    #pragma unroll
    for (int jf = 0; jf < 4; ++jf)
      b8[jf] = *(const half8*)&s.u.m.B[l>>4][joff + jf*16 + (l&15)][0];
    #pragma unroll
    for (int mf = 0; mf < 2; ++mf)
      #pragma unroll
      for (int jf = 0; jf < 4; ++jf)
        acc[mf][jf] = __builtin_amdgcn_mfma_f32_16x16x32_f16(a8[mf], b8[jf], acc[mf][jf], 0, 0, 0);
    __syncthreads();
  }

  // epilogue phase 1: BN0 + tanh -> x1[64][132] f32
  #pragma unroll
  for (int mf = 0; mf < 2; ++mf)
    #pragma unroll
    for (int jf = 0; jf < 4; ++jf)
      #pragma unroll
      for (int r = 0; r < 4; ++r) {
        int mm = moff + mf*16 + (l>>4)*4 + r;
        int jc = joff + jf*16 + (l&15);
        int d = jc & 63;
        s.u.e.x1[mm][jc] = tanhf(acc[mf][jf][r]*s.sc[d] + s.bi[d]);
      }
  __syncthreads();
  // epilogue phase 2: mini-GEMM over din=64 -> S1T
  const int tx = t & 31, ty = t >> 5;
  const int g64 = (tx >= 16) ? 64 : 0;
  const int dp = (tx & 15)*4;
  float e[8][4];
  #pragma unroll
  for (int r=0;r<8;++r)
    #pragma unroll
    for (int c=0;c<4;++c) e[r][c]=0.f;
  #pragma unroll 4
  for (int dd4 = 0; dd4 < 16; ++dd4) {
    float4 hb0 = *(const float4*)&s.ham1s[dd4*4+0][dp];
    float4 hb1 = *(const float4*)&s.ham1s[dd4*4+1][dp];
    float4 hb2 = *(const float4*)&s.ham1s[dd4*4+2][dp];
    float4 hb3 = *(const float4*)&s.ham1s[dd4*4+3][dp];
    #pragma unroll
    for (int r = 0; r < 8; ++r) {
      float4 xr = *(const float4*)&s.u.e.x1[ty*8+r][g64 + dd4*4];
      e[r][0] = fmaf(xr.x, hb0.x, fmaf(xr.y, hb1.x, fmaf(xr.z, hb2.x, fmaf(xr.w, hb3.x, e[r][0]))));
      e[r][1] = fmaf(xr.x, hb0.y, fmaf(xr.y, hb1.y, fmaf(xr.z, hb2.y, fmaf(xr.w, hb3.y, e[r][1]))));
      e[r][2] = fmaf(xr.x, hb0.z, fmaf(xr.y, hb1.z, fmaf(xr.z, hb2.z, fmaf(xr.w, hb3.z, e[r][2]))));
      e[r][3] = fmaf(xr.x, hb0.w, fmaf(xr.y, hb1.w, fmaf(xr.z, hb2.w, fmaf(xr.w, hb3.w, e[r][3]))));
    }
  }
  const int mbase = m0 + ty*8;
  if (mbase < MSTR) {
    #pragma unroll
    for (int c = 0; c < 4; ++c) {
      union { __half h[8]; uint4 v; } pk;
      #pragma unroll
      for (int r = 0; r < 8; ++r) pk.h[r] = __float2half(e[r][c]);
      int jout = j0 + g64 + dp + c;
      *(uint4*)(S1T + (size_t)jout*MSTR + mbase) = pk.v;
    }
  }
}

// ---------------- GEMM2 (MFMA): X2 = a_n @ S1; epi: BN1+tanh -> feat2 -------
struct SG2 {
  union {
    struct { __half A[4][64][8]; __half B[4][128][8]; } m;
    struct { __half x2[64][2][72]; } e;
  } u;
  float sc[64], bi[64];
};

__global__ __launch_bounds__(256) void k_gemm2(
    const __half* __restrict__ anG, const __half* __restrict__ S1T,
    const float* __restrict__ bng, const float* __restrict__ bnb,
    const float* __restrict__ bnm, const float* __restrict__ bnv,
    __half* __restrict__ feat2){
  __shared__ SG2 s;
  const int t = threadIdx.x;
  const int l = t & 63, wv = t >> 6;
  const int bidm = blockIdx.x / 768, bidj = blockIdx.x % 768;
  const int m0 = bidm*64, j0 = bidj*128;
  if (t < 64) {
    float sc = bng[64+t] / sqrtf(bnv[64+t] + 1e-5f);
    s.sc[t] = sc; s.bi[t] = bnb[64+t] - bnm[64+t]*sc;
  }
  const int jB = t >> 1, hB = t & 1;
  const int moff = (wv>>1)*32, joff = (wv&1)*64;

  f32x4 acc[2][4];
  #pragma unroll
  for (int a=0;a<2;++a)
    #pragma unroll
    for (int b=0;b<4;++b) acc[a][b] = (f32x4){0.f,0.f,0.f,0.f};

  for (int ks = 0; ks < 10; ++ks) {
    const int k0 = ks*32;
    uint4 av = *(const uint4*)(anG + ((((ks*4 + wv)*320) + m0 + l) << 3));
    const __half* bsrc = S1T + (size_t)(j0 + jB)*MSTR + k0 + hB*16;
    uint4 b0 = *(const uint4*)bsrc;
    uint4 b1 = *(const uint4*)(bsrc + 8);
    *(uint4*)&s.u.m.A[wv][l][0]        = av;
    *(uint4*)&s.u.m.B[hB*2][jB][0]     = b0;
    *(uint4*)&s.u.m.B[hB*2+1][jB][0]   = b1;
    __syncthreads();
    half8 a8[2], b8[4];
    #pragma unroll
    for (int mf = 0; mf < 2; ++mf)
      a8[mf] = *(const half8*)&s.u.m.A[l>>4][moff + mf*16 + (l&15)][0];
    #pragma unroll
    for (int jf = 0; jf < 4; ++jf)
      b8[jf] = *(const half8*)&s.u.m.B[l>>4][joff + jf*16 + (l&15)][0];
    #pragma unroll
    for (int mf = 0; mf < 2; ++mf)
      #pragma unroll
      for (int jf = 0; jf < 4; ++jf)
        acc[mf][jf] = __builtin_amdgcn_mfma_f32_16x16x32_f16(a8[mf], b8[jf], acc[mf][jf], 0, 0, 0);
    __syncthreads();
  }
  // BN1 + tanh -> x2[m][bl][d]
  #pragma unroll
  for (int mf = 0; mf < 2; ++mf)
    #pragma unroll
    for (int jf = 0; jf < 4; ++jf)
      #pragma unroll
      for (int r = 0; r < 4; ++r) {
        int mm = moff + mf*16 + (l>>4)*4 + r;
        int jc = joff + jf*16 + (l&15);
        int bl = jc >> 6, d = jc & 63;
        float v = tanhf(acc[mf][jf][r]*s.sc[d] + s.bi[d]);
        s.u.e.x2[mm][bl][d] = __float2half(v);
      }
  __syncthreads();
  {
    int pr = t >> 1, hf = t & 1;
    int mm = pr >> 1, bl = pr & 1;
    int n = m0 + mm;
    if (n < NND) {
      int jg = j0 + bl*64;
      int b = jg/768, lq = (jg/64)%12;
      __half* dst = feat2 + ((size_t)lq*NROWS + n*BBATCH + b)*F2S + hf*32;
      const __half* srcl = &s.u.e.x2[mm][bl][hf*32];
      #pragma unroll
      for (int i = 0; i < 4; ++i)
        *(uint4*)(dst + i*8) = *(const uint4*)(srcl + i*8);
    }
  }
}

// ---------------- GRU (MFMA, 12 steps) + ReLU + FC head ---------------------
__global__ __launch_bounds__(512, 2) void k_gru(
    const __half* __restrict__ feat2, const __half* __restrict__ wihP,
    const __half* __restrict__ whhP, const float* __restrict__ b_ih,
    const float* __restrict__ b_hh, const float* __restrict__ fc_w,
    const float* __restrict__ fc_b, float* __restrict__ out){
  __shared__ __half wih[10*192*8];
  __shared__ __half whh[8*192*8];
  __shared__ __half xt[10*64*8];
  __shared__ __half Hs[8*64*8];
  __shared__ __half zst[16];
  __shared__ float red[4][2][16];

  const int t = threadIdx.x;
  const int l = t & 63, wv = t >> 6;
  const int mt = wv >> 1, ng = wv & 1;
  const int row0 = blockIdx.x * 64;

  for (int i = t; i < 10*192; i += 512) ((uint4*)wih)[i] = ((const uint4*)wihP)[i];
  for (int i = t; i < 8*192; i += 512)  ((uint4*)whh)[i] = ((const uint4*)whhP)[i];
  for (int i = t; i < 8*64; i += 512)   ((uint4*)Hs)[i] = make_uint4(0,0,0,0);
  if (t < 2) ((uint4*)zst)[t] = make_uint4(0,0,0,0);

  float bR[2], bZ[2], bI[2], bH[2], fw[2];
  #pragma unroll
  for (int s2 = 0; s2 < 2; ++s2) {
    int d = ng*32 + s2*16 + (l & 15);
    bR[s2] = b_ih[d]     + b_hh[d];
    bZ[s2] = b_ih[64+d]  + b_hh[64+d];
    bI[s2] = b_ih[128+d];
    bH[s2] = b_hh[128+d];
    fw[s2] = fc_w[d];
  }
  const float fcb = fc_b[0];
  float hreg[8];
  #pragma unroll
  for (int i = 0; i < 8; ++i) hreg[i] = 0.f;

  const int rst = t >> 3, qst = t & 7;
  {
    const __half* src = feat2 + ((size_t)(row0 + rst))*F2S;
    *(uint4*)&xt[(qst*64 + rst)*8] = *(const uint4*)(src + qst*8);
    if (qst < 2) *(uint4*)&xt[((qst+8)*64 + rst)*8] = *(const uint4*)(src + (qst+8)*8);
  }
  __syncthreads();

  const int rowA = mt*16 + (l & 15);
  const int gq = l >> 4;
  const int colb = l & 15;
  const __half* axt0 = &xt[((0+gq)*64 + rowA)*8];
  const __half* axt1 = &xt[((4+gq)*64 + rowA)*8];
  const __half* axt2 = (gq < 2) ? &xt[((8+gq)*64 + rowA)*8] : zst;
  const __half* ah0  = &Hs[((0+gq)*64 + rowA)*8];
  const __half* ah1  = &Hs[((4+gq)*64 + rowA)*8];
  const __half* bi0  = &wih[((0+gq)*192 + colb)*8];
  const __half* bi1  = &wih[((4+gq)*192 + colb)*8];
  const __half* bi2  = (gq < 2) ? &wih[((8+gq)*192 + colb)*8] : zst;
  const int ntm2 = (gq < 2) ? 128 : 0;
  const __half* bh0  = &whh[((0+gq)*192 + colb)*8];
  const __half* bh1  = &whh[((4+gq)*192 + colb)*8];

  for (int ts = 0; ts < 12; ++ts) {
    half8 agi0 = *(const half8*)axt0;
    half8 agi1 = *(const half8*)axt1;
    half8 agi2 = *(const half8*)axt2;
    half8 agh0 = *(const half8*)ah0;
    half8 agh1 = *(const half8*)ah1;
    f32x4 aR[2], aZ[2], aIn[2], aHn[2];
    #pragma unroll
    for (int s2 = 0; s2 < 2; ++s2) {
      aR[s2] = (f32x4){0.f,0.f,0.f,0.f}; aZ[s2] = (f32x4){0.f,0.f,0.f,0.f};
      aIn[s2] = (f32x4){0.f,0.f,0.f,0.f}; aHn[s2] = (f32x4){0.f,0.f,0.f,0.f};
    }
    #pragma unroll
    for (int s2 = 0; s2 < 2; ++s2) {
      const int ntr = ng*2 + s2, ntz = 4 + ng*2 + s2, ntn = 8 + ng*2 + s2;
      aR[s2] = __builtin_amdgcn_mfma_f32_16x16x32_f16(agi0, *(const half8*)(bi0 + ntr*128), aR[s2], 0,0,0);
      aR[s2] = __builtin_amdgcn_mfma_f32_16x16x32_f16(agi1, *(const half8*)(bi1 + ntr*128), aR[s2], 0,0,0);
      aR[s2] = __builtin_amdgcn_mfma_f32_16x16x32_f16(agi2, *(const half8*)(bi2 + ntr*ntm2), aR[s2], 0,0,0);
      aR[s2] = __builtin_amdgcn_mfma_f32_16x16x32_f16(agh0, *(const half8*)(bh0 + ntr*128), aR[s2], 0,0,0);
      aR[s2] = __builtin_amdgcn_mfma_f32_16x16x32_f16(agh1, *(const half8*)(bh1 + ntr*128), aR[s2], 0,0,0);
      aZ[s2] = __builtin_amdgcn_mfma_f32_16x16x32_f16(agi0, *(const half8*)(bi0 + ntz*128), aZ[s2], 0,0,0);
      aZ[s2] = __builtin_amdgcn_mfma_f32_16x16x32_f16(agi1, *(const half8*)(bi1 + ntz*128), aZ[s2], 0,0,0);
      aZ[s2] = __builtin_amdgcn_mfma_f32_16x16x32_f16(agi2, *(const half8*)(bi2 + ntz*ntm2), aZ[s2], 0,0,0);
      aZ[s2] = __builtin_amdgcn_mfma_f32_16x16x32_f16(agh0, *(const half8*)(bh0 + ntz*128), aZ[s2], 0,0,0);
      aZ[s2] = __builtin_amdgcn_mfma_f32_16x16x32_f16(agh1, *(const half8*)(bh1 + ntz*128), aZ[s2], 0,0,0);
      aIn[s2] = __builtin_amdgcn_mfma_f32_16x16x32_f16(agi0, *(const half8*)(bi0 + ntn*128), aIn[s2], 0,0,0);
      aIn[s2] = __builtin_amdgcn_mfma_f32_16x16x32_f16(agi1, *(const half8*)(bi1 + ntn*128), aIn[s2], 0,0,0);
      aIn[s2] = __builtin_amdgcn_mfma_f32_16x16x32_f16(agi2, *(const half8*)(bi2 + ntn*ntm2), aIn[s2], 0,0,0);
      aHn[s2] = __builtin_amdgcn_mfma_f32_16x16x32_f16(agh0, *(const half8*)(bh0 + ntn*128), aHn[s2], 0,0,0);
      aHn[s2] = __builtin_amdgcn_mfma_f32_16x16x32_f16(agh1, *(const half8*)(bh1 + ntn*128), aHn[s2], 0,0,0);
    }
    float hnew[8];
    #pragma unroll
    for (int s2 = 0; s2 < 2; ++s2)
      #pragma unroll
      for (int rg = 0; rg < 4; ++rg) {
        const int i = s2*4 + rg;
        float pr = aR[s2][rg] + bR[s2];
        float pz = aZ[s2][rg] + bZ[s2];
        float pn = aIn[s2][rg] + bI[s2];
        float ph = aHn[s2][rg] + bH[s2];
        float r = 1.f / (1.f + exp2f(-1.44269504f * pr));
        float z = 1.f / (1.f + exp2f(-1.44269504f * pz));
        float e2 = exp2f(2.88539008f * (pn + r*ph));
        float nc = 1.f - 2.f/(e2 + 1.f);
        hnew[i] = (1.f - z)*nc + z*hreg[i];
        hreg[i] = hnew[i];
      }
    if (ts >= 9) {
      #pragma unroll
      for (int rg = 0; rg < 4; ++rg) {
        float p = fmaxf(hnew[rg],0.f)*fw[0] + fmaxf(hnew[4+rg],0.f)*fw[1];
        p += __shfl_xor(p, 1); p += __shfl_xor(p, 2);
        p += __shfl_xor(p, 4); p += __shfl_xor(p, 8);
        if (colb == 0) red[mt][ng][gq*4 + rg] = p;
      }
    }
    __syncthreads();
    if (ts >= 9 && ng == 0 && colb == 0) {
      #pragma unroll
      for (int rg = 0; rg < 4; ++rg) {
        int rr = gq*4 + rg;
        float sum = red[mt][0][rr] + red[mt][1][rr] + fcb;
        int grow = row0 + mt*16 + rr;
        out[((grow & 127)*3 + (ts-9))*NND + (grow >> 7)] = sum;
      }
    }
    if (ts < 11) {
      #pragma unroll
      for (int s2 = 0; s2 < 2; ++s2) {
        const int d = ng*32 + s2*16 + colb;
        #pragma unroll
        for (int rg = 0; rg < 4; ++rg) {
          int rw = mt*16 + gq*4 + rg;
          Hs[((d>>3)*64 + rw)*8 + (d&7)] = __float2half(hnew[s2*4+rg]);
        }
      }
      const __half* src = feat2 + ((size_t)(ts+1)*NROWS + row0 + rst)*F2S;
      *(uint4*)&xt[(qst*64 + rst)*8] = *(const uint4*)(src + qst*8);
      if (qst < 2) *(uint4*)&xt[((qst+8)*64 + rst)*8] = *(const uint4*)(src + (qst+8)*8);
    }
    __syncthreads();
  }
}

// ---------------------------------------------------------------------------
extern "C" void kernel_launch(void* const* d_in, const int* in_sizes, int n_in,
                              void* d_out, int out_size, void* d_ws, size_t ws_size,
                              hipStream_t stream) {
  const float* hist    = (const float*)d_in[0];
  const float* adj     = (const float*)d_in[1];
  const float* w0      = (const float*)d_in[2];
  const float* w1      = (const float*)d_in[3];
  const float* bng     = (const float*)d_in[4];
  const float* bnb     = (const float*)d_in[5];
  const float* bnm     = (const float*)d_in[6];
  const float* bnv     = (const float*)d_in[7];
  const float* tid_emb = (const float*)d_in[8];
  const float* dw_emb  = (const float*)d_in[9];
  const float* w_ih    = (const float*)d_in[10];
  const float* w_hh    = (const float*)d_in[11];
  const float* b_ih    = (const float*)d_in[12];
  const float* b_hh    = (const float*)d_in[13];
  const float* fc_w    = (const float*)d_in[14];
  const float* fc_b    = (const float*)d_in[15];

  float* wsf   = (float*)d_ws;
  float* dinv  = wsf + OFF_DINV;
  float* ham0T = wsf + OFF_HAM0;
  float* ham1  = wsf + OFF_HAM1;
  __half* wihP  = (__half*)(wsf + OFF_WIHP);
  __half* whhP  = (__half*)(wsf + OFF_WHHP);
  __half* anG   = (__half*)(wsf + OFF_ANG);
  __half* S1T   = (__half*)(wsf + OFF_S1T);
  __half* S0T   = (__half*)(wsf + OFF_S0T);
  __half* feat2 = (__half*)(wsf + OFF_FEATH);
  float* outp  = (float*)d_out;

  k_dinv  <<<NND, 64, 0, stream>>>(adj, dinv);
  k_anG   <<<(KPAD*KPAD + 255)/256, 256, 0, stream>>>(adj, dinv, anG);
  k_ham   <<<17, 256, 0, stream>>>(w0, w1, ham0T, ham1);
  k_wT    <<<108, 256, 0, stream>>>(w_ih, w_hh, wihP, whhP);
  k_s0    <<<BBATCH*LSEQ, 256, 0, stream>>>(hist, ham0T, S0T);
  k_gemm1 <<<5*768, 256, 0, stream>>>(anG, S0T, ham1, bng, bnb, bnm, bnv, S1T);
  // k_extras AFTER gemm1: feat2 aliases S0T
  k_extras<<<(LSEQ*NROWS + 255)/256, 256, 0, stream>>>(hist, tid_emb, dw_emb, feat2);
  k_gemm2 <<<5*768, 256, 0, stream>>>(anG, S1T, bng, bnb, bnm, bnv, feat2);
  k_gru   <<<NROWS/64, 512, 0, stream>>>(feat2, wihP, whhP, b_ih, b_hh, fc_w, fc_b, outp);
}

// Round 6
// 405.527 us; speedup vs baseline: 3.9987x; 1.0377x over previous
//
#include <hip/hip_runtime.h>
#include <hip/hip_fp16.h>

// ---------------------------------------------------------------------------
// QGNN traffic predictor. R6: XCD-aware j-major grid mapping (B-panel L2
// locality) + double-buffered LDS with register prefetch in both GEMMs.
// ---------------------------------------------------------------------------

#define NND 307
#define BBATCH 128
#define LSEQ 12
#define HIDN 64
#define JTOT (BBATCH*LSEQ*HIDN)   // 98304
#define NROWS (NND*BBATCH)        // 39296
#define KPAD 320
#define MSTR 312                  // S0T/S1T row stride (halves)
#define F2S 80                    // feat2 row stride (halves)

// workspace layout (float units)
#define OFF_DINV  0
#define OFF_HAM0  320
#define OFF_HAM1  576
#define OFF_WIHP  4672            // __half [10][192][8]
#define OFF_WHHP  12352           // __half [8][192][8]
#define OFF_ANG   18496           // __half anG [10][4][320][8] = 51200 fl
#define OFF_S1T   69696           // __half S1T [98304][312] = 15335424 fl
#define OFF_S0T   15405120        // __half S0T [98304][312]  (aliases feat2)
#define OFF_FEATH 15405120        // __half feat2 [12][39296][80] = 18862080 fl

typedef _Float16 half8 __attribute__((ext_vector_type(8)));
typedef float f32x4 __attribute__((ext_vector_type(4)));

// ---------------- adjacency normalization ----------------
__global__ void k_dinv(const float* __restrict__ adj, float* __restrict__ dinv){
  int n = blockIdx.x; int lane = threadIdx.x;
  float s = 0.f;
  for (int m = lane; m < NND; m += 64) s += adj[n*NND+m] + (m==n ? 1.f : 0.f);
  #pragma unroll
  for (int o = 32; o > 0; o >>= 1) s += __shfl_down(s, o);
  if (lane == 0) dinv[n] = 1.f/sqrtf(s);
}

// a_n fp16, granule-tiled: anG[((ks*4+g)*320 + row)*8 + j] = a_n[row][ks*32+g*8+j]
__global__ void k_anG(const float* __restrict__ adj, const float* __restrict__ dinv,
                      __half* __restrict__ anG){
  int id = blockIdx.x*256 + threadIdx.x;
  if (id >= KPAD*KPAD) return;
  int n = id / KPAD, m = id % KPAD;
  float v = 0.f;
  if (n < NND && m < NND)
    v = dinv[n] * (adj[n*NND+m] + (n==m ? 1.f : 0.f)) * dinv[m];
  int ks = m >> 5, g = (m >> 3) & 3, j = m & 7;
  anG[(((ks*4 + g)*320 + n) << 3) + j] = __float2half(v);
}

// ---------------- Hamilton matrices ----------------
__global__ void k_ham(const float* __restrict__ w0, const float* __restrict__ w1,
                      float* __restrict__ ham0T, float* __restrict__ ham1){
  const int  comp[4][4] = {{0,1,2,3},{1,0,3,2},{2,3,0,1},{3,2,1,0}};
  const float sgn[4][4] = {{1.f,1.f,1.f,1.f},{-1.f,1.f,1.f,-1.f},
                           {-1.f,-1.f,1.f,1.f},{-1.f,1.f,-1.f,1.f}};
  int id = blockIdx.x*256 + threadIdx.x;
  if (id < 64) {
    int d = id, qb = d>>4, cc = d&15;
    #pragma unroll
    for (int c = 0; c < 4; ++c)
      ham0T[d*4+c] = sgn[c][qb] * w0[comp[c][qb]*16 + cc];
  }
  int id1 = id - 256;
  if (id1 >= 0 && id1 < 4096) {
    int drow = id1 >> 6, d = id1 & 63;
    int pb = drow>>4, rr = drow&15, qb = d>>4, cc = d&15;
    ham1[id1] = sgn[pb][qb] * w1[rr*64 + comp[pb][qb]*16 + cc];
  }
}

// ---------------- GRU weight packing: [granule][col][8] fp16 ----------------
__global__ void k_wT(const float* __restrict__ w_ih, const float* __restrict__ w_hh,
                     __half* __restrict__ wihP, __half* __restrict__ whhP){
  int id = blockIdx.x*256 + threadIdx.x;
  if (id < 10*192*8) {
    int j = id & 7, col = (id >> 3) % 192, g = id / (192*8);
    int k = g*8 + j;
    wihP[id] = __float2half(k < 75 ? w_ih[col*75 + k] : 0.f);
  } else {
    int id2 = id - 10*192*8;
    if (id2 < 8*192*8) {
      int j = id2 & 7, col = (id2 >> 3) % 192, g = id2 / (192*8);
      whhP[id2] = __float2half(w_hh[col*64 + g*8 + j]);
    }
  }
}

// ---------------- S0T = (hist x ham0)^T : [j=(b,l,d)][k] fp16 ---------------
__global__ __launch_bounds__(256) void k_s0(const float* __restrict__ hist,
                                            const float* __restrict__ ham0Tg,
                                            __half* __restrict__ S0T){
  __shared__ float4 histL[320];
  const int t = threadIdx.x;
  const int bl = blockIdx.x;             // b*12 + l
  for (int k = t; k < 320; k += 256)
    histL[k] = (k < NND) ? *(const float4*)(hist + ((size_t)bl*NND + k)*4)
                         : make_float4(0.f,0.f,0.f,0.f);
  __syncthreads();
  if (t < 154) {
    const int k0 = 2*t;
    const float4 hA = histL[k0], hB = histL[k0+1];
    const size_t jb = (size_t)bl*64;
    for (int d = 0; d < 64; ++d) {
      float4 h0 = *(const float4*)(ham0Tg + d*4);   // uniform -> s_load
      float vA = hA.x*h0.x + hA.y*h0.y + hA.z*h0.z + hA.w*h0.w;
      float vB = hB.x*h0.x + hB.y*h0.y + hB.z*h0.z + hB.w*h0.w;
      __half2 p = __floats2half2_rn(vA, vB);
      if (k0 + 1 < NND) *(__half2*)(S0T + (jb + d)*MSTR + k0) = p;
      else              S0T[(jb + d)*MSTR + k0] = __low2half(p);
    }
  }
}

// ---------------- feat extras: speed + embeddings into feat2 cols 64..79 ----
__global__ void k_extras(const float* __restrict__ hist, const float* __restrict__ tid_emb,
                         const float* __restrict__ dw_emb, __half* __restrict__ feat2){
  int id = blockIdx.x*256 + threadIdx.x;   // over LSEQ*NROWS
  if (id >= LSEQ*NROWS) return;
  int lq = id / NROWS, row = id % NROWS;
  int n = row >> 7, b = row & 127;
  const float* h = hist + ((size_t)(b*LSEQ + lq)*NND + n)*4;
  union { __half h16[16]; uint4 v[2]; } u;
  u.h16[0] = __float2half(h[0]);
  int ti  = (int)rintf(h[1]*287.f);
  int dwi = (int)rintf(h[2]*6.f);
  #pragma unroll
  for (int c = 0; c < 5; ++c) u.h16[1+c] = __float2half(tid_emb[ti*5+c]);
  #pragma unroll
  for (int c = 0; c < 5; ++c) u.h16[6+c] = __float2half(dw_emb[dwi*5+c]);
  #pragma unroll
  for (int c = 11; c < 16; ++c) u.h16[c] = __float2half(0.f);
  uint4* dst = (uint4*)(feat2 + (size_t)id*F2S + 64);
  dst[0] = u.v[0]; dst[1] = u.v[1];
}

// ---------------- GEMM1 (MFMA): X1 = a_n @ S0; epi: BN0+tanh, @ham1 -> S1T --
struct SG1 {
  union {
    struct { __half A[2][4][64][8]; __half B[2][4][128][8]; } m;  // 24576B
    struct { float x1[64][132]; } e;                              // 33792B
  } u;
  float ham1s[64][64];
  float sc[64], bi[64];
};

__global__ __launch_bounds__(256) void k_gemm1(
    const __half* __restrict__ anG, const __half* __restrict__ S0T,
    const float* __restrict__ ham1g,
    const float* __restrict__ bng, const float* __restrict__ bnb,
    const float* __restrict__ bnm, const float* __restrict__ bnv,
    __half* __restrict__ S1T){
  __shared__ SG1 s;
  const int t = threadIdx.x;
  const int l = t & 63, wv = t >> 6;
  // XCD-aware j-major mapping: same-j blocks adjacent on one XCD
  const int xcd = blockIdx.x & 7, idx = blockIdx.x >> 3;
  const int bidj = xcd*96 + idx/5, bidm = idx % 5;
  const int m0 = bidm*64, j0 = bidj*128;
  if (t < 64) {
    float sc = bng[t] / sqrtf(bnv[t] + 1e-5f);
    s.sc[t] = sc; s.bi[t] = bnb[t] - bnm[t]*sc;
  }
  for (int i = t; i < 4096; i += 256) (&s.ham1s[0][0])[i] = ham1g[i];

  const int jB = t >> 1, hB = t & 1;      // B staging: row jB, k-half hB
  const int moff = (wv>>1)*32, joff = (wv&1)*64;

  f32x4 acc[2][4];
  #pragma unroll
  for (int a=0;a<2;++a)
    #pragma unroll
    for (int b=0;b<4;++b) acc[a][b] = (f32x4){0.f,0.f,0.f,0.f};

  // prologue: stage ks=0 into buf0
  {
    uint4 av = *(const uint4*)(anG + (((wv*320) + m0 + l) << 3));
    const __half* bs = S0T + (size_t)(j0 + jB)*MSTR + hB*16;
    uint4 b0 = *(const uint4*)bs;
    uint4 b1 = *(const uint4*)(bs + 8);
    *(uint4*)&s.u.m.A[0][wv][l][0]      = av;
    *(uint4*)&s.u.m.B[0][hB*2][jB][0]   = b0;
    *(uint4*)&s.u.m.B[0][hB*2+1][jB][0] = b1;
  }
  __syncthreads();

  int cur = 0;
  for (int ks = 0; ks < 10; ++ks) {
    uint4 nav, nb0, nb1;
    if (ks < 9) {                        // prefetch ks+1 (latency under MFMA)
      nav = *(const uint4*)(anG + ((((ks+1)*4 + wv)*320 + m0 + l) << 3));
      const __half* bs = S0T + (size_t)(j0 + jB)*MSTR + (ks+1)*32 + hB*16;
      nb0 = *(const uint4*)bs;
      nb1 = *(const uint4*)(bs + 8);
    }
    half8 a8[2], b8[4];
    #pragma unroll
    for (int mf = 0; mf < 2; ++mf)
      a8[mf] = *(const half8*)&s.u.m.A[cur][l>>4][moff + mf*16 + (l&15)][0];
    #pragma unroll
    for (int jf = 0; jf < 4; ++jf)
      b8[jf] = *(const half8*)&s.u.m.B[cur][l>>4][joff + jf*16 + (l&15)][0];
    #pragma unroll
    for (int mf = 0; mf < 2; ++mf)
      #pragma unroll
      for (int jf = 0; jf < 4; ++jf)
        acc[mf][jf] = __builtin_amdgcn_mfma_f32_16x16x32_f16(a8[mf], b8[jf], acc[mf][jf], 0, 0, 0);
    if (ks < 9) {
      *(uint4*)&s.u.m.A[cur^1][wv][l][0]      = nav;
      *(uint4*)&s.u.m.B[cur^1][hB*2][jB][0]   = nb0;
      *(uint4*)&s.u.m.B[cur^1][hB*2+1][jB][0] = nb1;
      __syncthreads();                   // single barrier per K-step
      cur ^= 1;
    }
  }
  __syncthreads();                       // main tiles dead; union reuse safe

  // epilogue phase 1: BN0 + tanh -> x1[64][132] f32
  #pragma unroll
  for (int mf = 0; mf < 2; ++mf)
    #pragma unroll
    for (int jf = 0; jf < 4; ++jf)
      #pragma unroll
      for (int r = 0; r < 4; ++r) {
        int mm = moff + mf*16 + (l>>4)*4 + r;
        int jc = joff + jf*16 + (l&15);
        int d = jc & 63;
        s.u.e.x1[mm][jc] = tanhf(acc[mf][jf][r]*s.sc[d] + s.bi[d]);
      }
  __syncthreads();
  // epilogue phase 2: mini-GEMM over din=64 -> S1T
  const int tx = t & 31, ty = t >> 5;
  const int g64 = (tx >= 16) ? 64 : 0;
  const int dp = (tx & 15)*4;
  float e[8][4];
  #pragma unroll
  for (int r=0;r<8;++r)
    #pragma unroll
    for (int c=0;c<4;++c) e[r][c]=0.f;
  #pragma unroll 4
  for (int dd4 = 0; dd4 < 16; ++dd4) {
    float4 hb0 = *(const float4*)&s.ham1s[dd4*4+0][dp];
    float4 hb1 = *(const float4*)&s.ham1s[dd4*4+1][dp];
    float4 hb2 = *(const float4*)&s.ham1s[dd4*4+2][dp];
    float4 hb3 = *(const float4*)&s.ham1s[dd4*4+3][dp];
    #pragma unroll
    for (int r = 0; r < 8; ++r) {
      float4 xr = *(const float4*)&s.u.e.x1[ty*8+r][g64 + dd4*4];
      e[r][0] = fmaf(xr.x, hb0.x, fmaf(xr.y, hb1.x, fmaf(xr.z, hb2.x, fmaf(xr.w, hb3.x, e[r][0]))));
      e[r][1] = fmaf(xr.x, hb0.y, fmaf(xr.y, hb1.y, fmaf(xr.z, hb2.y, fmaf(xr.w, hb3.y, e[r][1]))));
      e[r][2] = fmaf(xr.x, hb0.z, fmaf(xr.y, hb1.z, fmaf(xr.z, hb2.z, fmaf(xr.w, hb3.z, e[r][2]))));
      e[r][3] = fmaf(xr.x, hb0.w, fmaf(xr.y, hb1.w, fmaf(xr.z, hb2.w, fmaf(xr.w, hb3.w, e[r][3]))));
    }
  }
  const int mbase = m0 + ty*8;
  if (mbase < MSTR) {
    #pragma unroll
    for (int c = 0; c < 4; ++c) {
      union { __half h[8]; uint4 v; } pk;
      #pragma unroll
      for (int r = 0; r < 8; ++r) pk.h[r] = __float2half(e[r][c]);
      int jout = j0 + g64 + dp + c;
      *(uint4*)(S1T + (size_t)jout*MSTR + mbase) = pk.v;
    }
  }
}

// ---------------- GEMM2 (MFMA): X2 = a_n @ S1; epi: BN1+tanh -> feat2 -------
struct SG2 {
  union {
    struct { __half A[2][4][64][8]; __half B[2][4][128][8]; } m;  // 24576B
    struct { __half x2[64][2][72]; } e;                           // 18432B
  } u;
  float sc[64], bi[64];
};

__global__ __launch_bounds__(256) void k_gemm2(
    const __half* __restrict__ anG, const __half* __restrict__ S1T,
    const float* __restrict__ bng, const float* __restrict__ bnb,
    const float* __restrict__ bnm, const float* __restrict__ bnv,
    __half* __restrict__ feat2){
  __shared__ SG2 s;
  const int t = threadIdx.x;
  const int l = t & 63, wv = t >> 6;
  const int xcd = blockIdx.x & 7, idx = blockIdx.x >> 3;
  const int bidj = xcd*96 + idx/5, bidm = idx % 5;
  const int m0 = bidm*64, j0 = bidj*128;
  if (t < 64) {
    float sc = bng[64+t] / sqrtf(bnv[64+t] + 1e-5f);
    s.sc[t] = sc; s.bi[t] = bnb[64+t] - bnm[64+t]*sc;
  }
  const int jB = t >> 1, hB = t & 1;
  const int moff = (wv>>1)*32, joff = (wv&1)*64;

  f32x4 acc[2][4];
  #pragma unroll
  for (int a=0;a<2;++a)
    #pragma unroll
    for (int b=0;b<4;++b) acc[a][b] = (f32x4){0.f,0.f,0.f,0.f};

  {
    uint4 av = *(const uint4*)(anG + (((wv*320) + m0 + l) << 3));
    const __half* bs = S1T + (size_t)(j0 + jB)*MSTR + hB*16;
    uint4 b0 = *(const uint4*)bs;
    uint4 b1 = *(const uint4*)(bs + 8);
    *(uint4*)&s.u.m.A[0][wv][l][0]      = av;
    *(uint4*)&s.u.m.B[0][hB*2][jB][0]   = b0;
    *(uint4*)&s.u.m.B[0][hB*2+1][jB][0] = b1;
  }
  __syncthreads();

  int cur = 0;
  for (int ks = 0; ks < 10; ++ks) {
    uint4 nav, nb0, nb1;
    if (ks < 9) {
      nav = *(const uint4*)(anG + ((((ks+1)*4 + wv)*320 + m0 + l) << 3));
      const __half* bs = S1T + (size_t)(j0 + jB)*MSTR + (ks+1)*32 + hB*16;
      nb0 = *(const uint4*)bs;
      nb1 = *(const uint4*)(bs + 8);
    }
    half8 a8[2], b8[4];
    #pragma unroll
    for (int mf = 0; mf < 2; ++mf)
      a8[mf] = *(const half8*)&s.u.m.A[cur][l>>4][moff + mf*16 + (l&15)][0];
    #pragma unroll
    for (int jf = 0; jf < 4; ++jf)
      b8[jf] = *(const half8*)&s.u.m.B[cur][l>>4][joff + jf*16 + (l&15)][0];
    #pragma unroll
    for (int mf = 0; mf < 2; ++mf)
      #pragma unroll
      for (int jf = 0; jf < 4; ++jf)
        acc[mf][jf] = __builtin_amdgcn_mfma_f32_16x16x32_f16(a8[mf], b8[jf], acc[mf][jf], 0, 0, 0);
    if (ks < 9) {
      *(uint4*)&s.u.m.A[cur^1][wv][l][0]      = nav;
      *(uint4*)&s.u.m.B[cur^1][hB*2][jB][0]   = nb0;
      *(uint4*)&s.u.m.B[cur^1][hB*2+1][jB][0] = nb1;
      __syncthreads();
      cur ^= 1;
    }
  }
  __syncthreads();
  // BN1 + tanh -> x2[m][bl][d]
  #pragma unroll
  for (int mf = 0; mf < 2; ++mf)
    #pragma unroll
    for (int jf = 0; jf < 4; ++jf)
      #pragma unroll
      for (int r = 0; r < 4; ++r) {
        int mm = moff + mf*16 + (l>>4)*4 + r;
        int jc = joff + jf*16 + (l&15);
        int bl = jc >> 6, d = jc & 63;
        float v = tanhf(acc[mf][jf][r]*s.sc[d] + s.bi[d]);
        s.u.e.x2[mm][bl][d] = __float2half(v);
      }
  __syncthreads();
  {
    int pr = t >> 1, hf = t & 1;
    int mm = pr >> 1, bl = pr & 1;
    int n = m0 + mm;
    if (n < NND) {
      int jg = j0 + bl*64;
      int b = jg/768, lq = (jg/64)%12;
      __half* dst = feat2 + ((size_t)lq*NROWS + n*BBATCH + b)*F2S + hf*32;
      const __half* srcl = &s.u.e.x2[mm][bl][hf*32];
      #pragma unroll
      for (int i = 0; i < 4; ++i)
        *(uint4*)(dst + i*8) = *(const uint4*)(srcl + i*8);
    }
  }
}

// ---------------- GRU (MFMA, 12 steps) + ReLU + FC head ---------------------
__global__ __launch_bounds__(512, 2) void k_gru(
    const __half* __restrict__ feat2, const __half* __restrict__ wihP,
    const __half* __restrict__ whhP, const float* __restrict__ b_ih,
    const float* __restrict__ b_hh, const float* __restrict__ fc_w,
    const float* __restrict__ fc_b, float* __restrict__ out){
  __shared__ __half wih[10*192*8];
  __shared__ __half whh[8*192*8];
  __shared__ __half xt[10*64*8];
  __shared__ __half Hs[8*64*8];
  __shared__ __half zst[16];
  __shared__ float red[4][2][16];

  const int t = threadIdx.x;
  const int l = t & 63, wv = t >> 6;
  const int mt = wv >> 1, ng = wv & 1;
  const int row0 = blockIdx.x * 64;

  for (int i = t; i < 10*192; i += 512) ((uint4*)wih)[i] = ((const uint4*)wihP)[i];
  for (int i = t; i < 8*192; i += 512)  ((uint4*)whh)[i] = ((const uint4*)whhP)[i];
  for (int i = t; i < 8*64; i += 512)   ((uint4*)Hs)[i] = make_uint4(0,0,0,0);
  if (t < 2) ((uint4*)zst)[t] = make_uint4(0,0,0,0);

  float bR[2], bZ[2], bI[2], bH[2], fw[2];
  #pragma unroll
  for (int s2 = 0; s2 < 2; ++s2) {
    int d = ng*32 + s2*16 + (l & 15);
    bR[s2] = b_ih[d]     + b_hh[d];
    bZ[s2] = b_ih[64+d]  + b_hh[64+d];
    bI[s2] = b_ih[128+d];
    bH[s2] = b_hh[128+d];
    fw[s2] = fc_w[d];
  }
  const float fcb = fc_b[0];
  float hreg[8];
  #pragma unroll
  for (int i = 0; i < 8; ++i) hreg[i] = 0.f;

  const int rst = t >> 3, qst = t & 7;
  {
    const __half* src = feat2 + ((size_t)(row0 + rst))*F2S;
    *(uint4*)&xt[(qst*64 + rst)*8] = *(const uint4*)(src + qst*8);
    if (qst < 2) *(uint4*)&xt[((qst+8)*64 + rst)*8] = *(const uint4*)(src + (qst+8)*8);
  }
  __syncthreads();

  const int rowA = mt*16 + (l & 15);
  const int gq = l >> 4;
  const int colb = l & 15;
  const __half* axt0 = &xt[((0+gq)*64 + rowA)*8];
  const __half* axt1 = &xt[((4+gq)*64 + rowA)*8];
  const __half* axt2 = (gq < 2) ? &xt[((8+gq)*64 + rowA)*8] : zst;
  const __half* ah0  = &Hs[((0+gq)*64 + rowA)*8];
  const __half* ah1  = &Hs[((4+gq)*64 + rowA)*8];
  const __half* bi0  = &wih[((0+gq)*192 + colb)*8];
  const __half* bi1  = &wih[((4+gq)*192 + colb)*8];
  const __half* bi2  = (gq < 2) ? &wih[((8+gq)*192 + colb)*8] : zst;
  const int ntm2 = (gq < 2) ? 128 : 0;
  const __half* bh0  = &whh[((0+gq)*192 + colb)*8];
  const __half* bh1  = &whh[((4+gq)*192 + colb)*8];

  for (int ts = 0; ts < 12; ++ts) {
    half8 agi0 = *(const half8*)axt0;
    half8 agi1 = *(const half8*)axt1;
    half8 agi2 = *(const half8*)axt2;
    half8 agh0 = *(const half8*)ah0;
    half8 agh1 = *(const half8*)ah1;
    f32x4 aR[2], aZ[2], aIn[2], aHn[2];
    #pragma unroll
    for (int s2 = 0; s2 < 2; ++s2) {
      aR[s2] = (f32x4){0.f,0.f,0.f,0.f}; aZ[s2] = (f32x4){0.f,0.f,0.f,0.f};
      aIn[s2] = (f32x4){0.f,0.f,0.f,0.f}; aHn[s2] = (f32x4){0.f,0.f,0.f,0.f};
    }
    #pragma unroll
    for (int s2 = 0; s2 < 2; ++s2) {
      const int ntr = ng*2 + s2, ntz = 4 + ng*2 + s2, ntn = 8 + ng*2 + s2;
      aR[s2] = __builtin_amdgcn_mfma_f32_16x16x32_f16(agi0, *(const half8*)(bi0 + ntr*128), aR[s2], 0,0,0);
      aR[s2] = __builtin_amdgcn_mfma_f32_16x16x32_f16(agi1, *(const half8*)(bi1 + ntr*128), aR[s2], 0,0,0);
      aR[s2] = __builtin_amdgcn_mfma_f32_16x16x32_f16(agi2, *(const half8*)(bi2 + ntr*ntm2), aR[s2], 0,0,0);
      aR[s2] = __builtin_amdgcn_mfma_f32_16x16x32_f16(agh0, *(const half8*)(bh0 + ntr*128), aR[s2], 0,0,0);
      aR[s2] = __builtin_amdgcn_mfma_f32_16x16x32_f16(agh1, *(const half8*)(bh1 + ntr*128), aR[s2], 0,0,0);
      aZ[s2] = __builtin_amdgcn_mfma_f32_16x16x32_f16(agi0, *(const half8*)(bi0 + ntz*128), aZ[s2], 0,0,0);
      aZ[s2] = __builtin_amdgcn_mfma_f32_16x16x32_f16(agi1, *(const half8*)(bi1 + ntz*128), aZ[s2], 0,0,0);
      aZ[s2] = __builtin_amdgcn_mfma_f32_16x16x32_f16(agi2, *(const half8*)(bi2 + ntz*ntm2), aZ[s2], 0,0,0);
      aZ[s2] = __builtin_amdgcn_mfma_f32_16x16x32_f16(agh0, *(const half8*)(bh0 + ntz*128), aZ[s2], 0,0,0);
      aZ[s2] = __builtin_amdgcn_mfma_f32_16x16x32_f16(agh1, *(const half8*)(bh1 + ntz*128), aZ[s2], 0,0,0);
      aIn[s2] = __builtin_amdgcn_mfma_f32_16x16x32_f16(agi0, *(const half8*)(bi0 + ntn*128), aIn[s2], 0,0,0);
      aIn[s2] = __builtin_amdgcn_mfma_f32_16x16x32_f16(agi1, *(const half8*)(bi1 + ntn*128), aIn[s2], 0,0,0);
      aIn[s2] = __builtin_amdgcn_mfma_f32_16x16x32_f16(agi2, *(const half8*)(bi2 + ntn*ntm2), aIn[s2], 0,0,0);
      aHn[s2] = __builtin_amdgcn_mfma_f32_16x16x32_f16(agh0, *(const half8*)(bh0 + ntn*128), aHn[s2], 0,0,0);
      aHn[s2] = __builtin_amdgcn_mfma_f32_16x16x32_f16(agh1, *(const half8*)(bh1 + ntn*128), aHn[s2], 0,0,0);
    }
    float hnew[8];
    #pragma unroll
    for (int s2 = 0; s2 < 2; ++s2)
      #pragma unroll
      for (int rg = 0; rg < 4; ++rg) {
        const int i = s2*4 + rg;
        float pr = aR[s2][rg] + bR[s2];
        float pz = aZ[s2][rg] + bZ[s2];
        float pn = aIn[s2][rg] + bI[s2];
        float ph = aHn[s2][rg] + bH[s2];
        float r = 1.f / (1.f + exp2f(-1.44269504f * pr));
        float z = 1.f / (1.f + exp2f(-1.44269504f * pz));
        float e2 = exp2f(2.88539008f * (pn + r*ph));
        float nc = 1.f - 2.f/(e2 + 1.f);
        hnew[i] = (1.f - z)*nc + z*hreg[i];
        hreg[i] = hnew[i];
      }
    if (ts >= 9) {
      #pragma unroll
      for (int rg = 0; rg < 4; ++rg) {
        float p = fmaxf(hnew[rg],0.f)*fw[0] + fmaxf(hnew[4+rg],0.f)*fw[1];
        p += __shfl_xor(p, 1); p += __shfl_xor(p, 2);
        p += __shfl_xor(p, 4); p += __shfl_xor(p, 8);
        if (colb == 0) red[mt][ng][gq*4 + rg] = p;
      }
    }
    __syncthreads();
    if (ts >= 9 && ng == 0 && colb == 0) {
      #pragma unroll
      for (int rg = 0; rg < 4; ++rg) {
        int rr = gq*4 + rg;
        float sum = red[mt][0][rr] + red[mt][1][rr] + fcb;
        int grow = row0 + mt*16 + rr;
        out[((grow & 127)*3 + (ts-9))*NND + (grow >> 7)] = sum;
      }
    }
    if (ts < 11) {
      #pragma unroll
      for (int s2 = 0; s2 < 2; ++s2) {
        const int d = ng*32 + s2*16 + colb;
        #pragma unroll
        for (int rg = 0; rg < 4; ++rg) {
          int rw = mt*16 + gq*4 + rg;
          Hs[((d>>3)*64 + rw)*8 + (d&7)] = __float2half(hnew[s2*4+rg]);
        }
      }
      const __half* src = feat2 + ((size_t)(ts+1)*NROWS + row0 + rst)*F2S;
      *(uint4*)&xt[(qst*64 + rst)*8] = *(const uint4*)(src + qst*8);
      if (qst < 2) *(uint4*)&xt[((qst+8)*64 + rst)*8] = *(const uint4*)(src + (qst+8)*8);
    }
    __syncthreads();
  }
}

// ---------------------------------------------------------------------------
extern "C" void kernel_launch(void* const* d_in, const int* in_sizes, int n_in,
                              void* d_out, int out_size, void* d_ws, size_t ws_size,
                              hipStream_t stream) {
  const float* hist    = (const float*)d_in[0];
  const float* adj     = (const float*)d_in[1];
  const float* w0      = (const float*)d_in[2];
  const float* w1      = (const float*)d_in[3];
  const float* bng     = (const float*)d_in[4];
  const float* bnb     = (const float*)d_in[5];
  const float* bnm     = (const float*)d_in[6];
  const float* bnv     = (const float*)d_in[7];
  const float* tid_emb = (const float*)d_in[8];
  const float* dw_emb  = (const float*)d_in[9];
  const float* w_ih    = (const float*)d_in[10];
  const float* w_hh    = (const float*)d_in[11];
  const float* b_ih    = (const float*)d_in[12];
  const float* b_hh    = (const float*)d_in[13];
  const float* fc_w    = (const float*)d_in[14];
  const float* fc_b    = (const float*)d_in[15];

  float* wsf   = (float*)d_ws;
  float* dinv  = wsf + OFF_DINV;
  float* ham0T = wsf + OFF_HAM0;
  float* ham1  = wsf + OFF_HAM1;
  __half* wihP  = (__half*)(wsf + OFF_WIHP);
  __half* whhP  = (__half*)(wsf + OFF_WHHP);
  __half* anG   = (__half*)(wsf + OFF_ANG);
  __half* S1T   = (__half*)(wsf + OFF_S1T);
  __half* S0T   = (__half*)(wsf + OFF_S0T);
  __half* feat2 = (__half*)(wsf + OFF_FEATH);
  float* outp  = (float*)d_out;

  k_dinv  <<<NND, 64, 0, stream>>>(adj, dinv);
  k_anG   <<<(KPAD*KPAD + 255)/256, 256, 0, stream>>>(adj, dinv, anG);
  k_ham   <<<17, 256, 0, stream>>>(w0, w1, ham0T, ham1);
  k_wT    <<<108, 256, 0, stream>>>(w_ih, w_hh, wihP, whhP);
  k_s0    <<<BBATCH*LSEQ, 256, 0, stream>>>(hist, ham0T, S0T);
  k_gemm1 <<<5*768, 256, 0, stream>>>(anG, S0T, ham1, bng, bnb, bnm, bnv, S1T);
  // k_extras AFTER gemm1: feat2 aliases S0T
  k_extras<<<(LSEQ*NROWS + 255)/256, 256, 0, stream>>>(hist, tid_emb, dw_emb, feat2);
  k_gemm2 <<<5*768, 256, 0, stream>>>(anG, S1T, bng, bnb, bnm, bnv, feat2);
  k_gru   <<<NROWS/64, 512, 0, stream>>>(feat2, wihP, whhP, b_ih, b_hh, fc_w, fc_b, outp);
}

// Round 7
// 333.521 us; speedup vs baseline: 4.8620x; 1.2159x over previous
//
#include <hip/hip_runtime.h>
#include <hip/hip_fp16.h>

// ---------------------------------------------------------------------------
// QGNN traffic predictor. R7: gemm1 epilogue mini-GEMM (S1 = x1 @ ham1) moved
// to MFMA (fp16 xh/ham1B, granule layout); cheap tanh (exp2) in GEMM epilogues.
// ---------------------------------------------------------------------------

#define NND 307
#define BBATCH 128
#define LSEQ 12
#define HIDN 64
#define JTOT (BBATCH*LSEQ*HIDN)   // 98304
#define NROWS (NND*BBATCH)        // 39296
#define KPAD 320
#define MSTR 312                  // S0T/S1T row stride (halves)
#define F2S 80                    // feat2 row stride (halves)

// workspace layout (float units)
#define OFF_DINV  0
#define OFF_HAM0  320
#define OFF_HAM1B 576             // __half ham1B [8][64][8] = 2048 fl
#define OFF_WIHP  4672            // __half [10][192][8]
#define OFF_WHHP  12352           // __half [8][192][8]
#define OFF_ANG   18496           // __half anG [10][4][320][8] = 51200 fl
#define OFF_S1T   69696           // __half S1T [98304][312] = 15335424 fl
#define OFF_S0T   15405120        // __half S0T [98304][312]  (aliases feat2)
#define OFF_FEATH 15405120        // __half feat2 [12][39296][80] = 18862080 fl

typedef _Float16 half8 __attribute__((ext_vector_type(8)));
typedef float f32x4 __attribute__((ext_vector_type(4)));

__device__ __forceinline__ float tanh_fast(float v){
  float e2 = exp2f(2.88539008f * v);     // exp(2v)
  return 1.f - 2.f/(e2 + 1.f);
}

// ---------------- adjacency normalization ----------------
__global__ void k_dinv(const float* __restrict__ adj, float* __restrict__ dinv){
  int n = blockIdx.x; int lane = threadIdx.x;
  float s = 0.f;
  for (int m = lane; m < NND; m += 64) s += adj[n*NND+m] + (m==n ? 1.f : 0.f);
  #pragma unroll
  for (int o = 32; o > 0; o >>= 1) s += __shfl_down(s, o);
  if (lane == 0) dinv[n] = 1.f/sqrtf(s);
}

// a_n fp16, granule-tiled: anG[((ks*4+g)*320 + row)*8 + j] = a_n[row][ks*32+g*8+j]
__global__ void k_anG(const float* __restrict__ adj, const float* __restrict__ dinv,
                      __half* __restrict__ anG){
  int id = blockIdx.x*256 + threadIdx.x;
  if (id >= KPAD*KPAD) return;
  int n = id / KPAD, m = id % KPAD;
  float v = 0.f;
  if (n < NND && m < NND)
    v = dinv[n] * (adj[n*NND+m] + (n==m ? 1.f : 0.f)) * dinv[m];
  int ks = m >> 5, g = (m >> 3) & 3, j = m & 7;
  anG[(((ks*4 + g)*320 + n) << 3) + j] = __float2half(v);
}

// ---------------- Hamilton matrices (ham0T f32; ham1 -> fp16 B-granule) -----
__global__ void k_ham(const float* __restrict__ w0, const float* __restrict__ w1,
                      float* __restrict__ ham0T, __half* __restrict__ ham1B){
  const int  comp[4][4] = {{0,1,2,3},{1,0,3,2},{2,3,0,1},{3,2,1,0}};
  const float sgn[4][4] = {{1.f,1.f,1.f,1.f},{-1.f,1.f,1.f,-1.f},
                           {-1.f,-1.f,1.f,1.f},{-1.f,1.f,-1.f,1.f}};
  int id = blockIdx.x*256 + threadIdx.x;
  if (id < 64) {
    int d = id, qb = d>>4, cc = d&15;
    #pragma unroll
    for (int c = 0; c < 4; ++c)
      ham0T[d*4+c] = sgn[c][qb] * w0[comp[c][qb]*16 + cc];
  }
  int id1 = id - 256;
  if (id1 >= 0 && id1 < 4096) {
    int din = id1 >> 6, d = id1 & 63;      // ham1[din][dout=d]
    int pb = din>>4, rr = din&15, qb = d>>4, cc = d&15;
    float val = sgn[pb][qb] * w1[rr*64 + comp[pb][qb]*16 + cc];
    ham1B[(((din>>3)*64) + d)*8 + (din&7)] = __float2half(val);
  }
}

// ---------------- GRU weight packing: [granule][col][8] fp16 ----------------
__global__ void k_wT(const float* __restrict__ w_ih, const float* __restrict__ w_hh,
                     __half* __restrict__ wihP, __half* __restrict__ whhP){
  int id = blockIdx.x*256 + threadIdx.x;
  if (id < 10*192*8) {
    int j = id & 7, col = (id >> 3) % 192, g = id / (192*8);
    int k = g*8 + j;
    wihP[id] = __float2half(k < 75 ? w_ih[col*75 + k] : 0.f);
  } else {
    int id2 = id - 10*192*8;
    if (id2 < 8*192*8) {
      int j = id2 & 7, col = (id2 >> 3) % 192, g = id2 / (192*8);
      whhP[id2] = __float2half(w_hh[col*64 + g*8 + j]);
    }
  }
}

// ---------------- S0T = (hist x ham0)^T : [j=(b,l,d)][k] fp16 ---------------
__global__ __launch_bounds__(256) void k_s0(const float* __restrict__ hist,
                                            const float* __restrict__ ham0Tg,
                                            __half* __restrict__ S0T){
  __shared__ float4 histL[320];
  const int t = threadIdx.x;
  const int bl = blockIdx.x;             // b*12 + l
  for (int k = t; k < 320; k += 256)
    histL[k] = (k < NND) ? *(const float4*)(hist + ((size_t)bl*NND + k)*4)
                         : make_float4(0.f,0.f,0.f,0.f);
  __syncthreads();
  if (t < 154) {
    const int k0 = 2*t;
    const float4 hA = histL[k0], hB = histL[k0+1];
    const size_t jb = (size_t)bl*64;
    for (int d = 0; d < 64; ++d) {
      float4 h0 = *(const float4*)(ham0Tg + d*4);   // uniform -> s_load
      float vA = hA.x*h0.x + hA.y*h0.y + hA.z*h0.z + hA.w*h0.w;
      float vB = hB.x*h0.x + hB.y*h0.y + hB.z*h0.z + hB.w*h0.w;
      __half2 p = __floats2half2_rn(vA, vB);
      if (k0 + 1 < NND) *(__half2*)(S0T + (jb + d)*MSTR + k0) = p;
      else              S0T[(jb + d)*MSTR + k0] = __low2half(p);
    }
  }
}

// ---------------- feat extras: speed + embeddings into feat2 cols 64..79 ----
__global__ void k_extras(const float* __restrict__ hist, const float* __restrict__ tid_emb,
                         const float* __restrict__ dw_emb, __half* __restrict__ feat2){
  int id = blockIdx.x*256 + threadIdx.x;   // over LSEQ*NROWS
  if (id >= LSEQ*NROWS) return;
  int lq = id / NROWS, row = id % NROWS;
  int n = row >> 7, b = row & 127;
  const float* h = hist + ((size_t)(b*LSEQ + lq)*NND + n)*4;
  union { __half h16[16]; uint4 v[2]; } u;
  u.h16[0] = __float2half(h[0]);
  int ti  = (int)rintf(h[1]*287.f);
  int dwi = (int)rintf(h[2]*6.f);
  #pragma unroll
  for (int c = 0; c < 5; ++c) u.h16[1+c] = __float2half(tid_emb[ti*5+c]);
  #pragma unroll
  for (int c = 0; c < 5; ++c) u.h16[6+c] = __float2half(dw_emb[dwi*5+c]);
  #pragma unroll
  for (int c = 11; c < 16; ++c) u.h16[c] = __float2half(0.f);
  uint4* dst = (uint4*)(feat2 + (size_t)id*F2S + 64);
  dst[0] = u.v[0]; dst[1] = u.v[1];
}

// ---------------- GEMM1 (MFMA): X1 = a_n @ S0; epi: BN0+tanh, @ham1 (MFMA) --
struct SG1 {
  union {
    struct { __half A[2][4][64][8]; __half B[2][4][128][8]; } m;              // 24576B
    struct { __half xh[2][8][64][8]; __half h1b[8][64][8]; __half s1l[128][72]; } e; // 43008B
  } u;
  float sc[64], bi[64];
};

__global__ __launch_bounds__(256) void k_gemm1(
    const __half* __restrict__ anG, const __half* __restrict__ S0T,
    const __half* __restrict__ ham1Bg,
    const float* __restrict__ bng, const float* __restrict__ bnb,
    const float* __restrict__ bnm, const float* __restrict__ bnv,
    __half* __restrict__ S1T){
  __shared__ SG1 s;
  const int t = threadIdx.x;
  const int l = t & 63, wv = t >> 6;
  // XCD-aware j-major mapping
  const int xcd = blockIdx.x & 7, idx = blockIdx.x >> 3;
  const int bidj = xcd*96 + idx/5, bidm = idx % 5;
  const int m0 = bidm*64, j0 = bidj*128;
  if (t < 64) {
    float sc = bng[t] / sqrtf(bnv[t] + 1e-5f);
    s.sc[t] = sc; s.bi[t] = bnb[t] - bnm[t]*sc;
  }

  const int jB = t >> 1, hB = t & 1;
  const int moff = (wv>>1)*32, joff = (wv&1)*64;

  f32x4 acc[2][4];
  #pragma unroll
  for (int a=0;a<2;++a)
    #pragma unroll
    for (int b=0;b<4;++b) acc[a][b] = (f32x4){0.f,0.f,0.f,0.f};

  {
    uint4 av = *(const uint4*)(anG + (((wv*320) + m0 + l) << 3));
    const __half* bs = S0T + (size_t)(j0 + jB)*MSTR + hB*16;
    uint4 b0 = *(const uint4*)bs;
    uint4 b1 = *(const uint4*)(bs + 8);
    *(uint4*)&s.u.m.A[0][wv][l][0]      = av;
    *(uint4*)&s.u.m.B[0][hB*2][jB][0]   = b0;
    *(uint4*)&s.u.m.B[0][hB*2+1][jB][0] = b1;
  }
  __syncthreads();

  int cur = 0;
  for (int ks = 0; ks < 10; ++ks) {
    uint4 nav, nb0, nb1;
    if (ks < 9) {
      nav = *(const uint4*)(anG + ((((ks+1)*4 + wv)*320 + m0 + l) << 3));
      const __half* bs = S0T + (size_t)(j0 + jB)*MSTR + (ks+1)*32 + hB*16;
      nb0 = *(const uint4*)bs;
      nb1 = *(const uint4*)(bs + 8);
    }
    half8 a8[2], b8[4];
    #pragma unroll
    for (int mf = 0; mf < 2; ++mf)
      a8[mf] = *(const half8*)&s.u.m.A[cur][l>>4][moff + mf*16 + (l&15)][0];
    #pragma unroll
    for (int jf = 0; jf < 4; ++jf)
      b8[jf] = *(const half8*)&s.u.m.B[cur][l>>4][joff + jf*16 + (l&15)][0];
    #pragma unroll
    for (int mf = 0; mf < 2; ++mf)
      #pragma unroll
      for (int jf = 0; jf < 4; ++jf)
        acc[mf][jf] = __builtin_amdgcn_mfma_f32_16x16x32_f16(a8[mf], b8[jf], acc[mf][jf], 0, 0, 0);
    if (ks < 9) {
      *(uint4*)&s.u.m.A[cur^1][wv][l][0]      = nav;
      *(uint4*)&s.u.m.B[cur^1][hB*2][jB][0]   = nb0;
      *(uint4*)&s.u.m.B[cur^1][hB*2+1][jB][0] = nb1;
      __syncthreads();
      cur ^= 1;
    }
  }
  __syncthreads();                       // main tiles dead; union reuse safe

  // stage ham1B (8KB) + BN0/tanh -> xh (fp16, A-granule layout)
  {
    const uint4* srcg = (const uint4*)ham1Bg;
    uint4* dstg = (uint4*)&s.u.e.h1b[0][0][0];
    #pragma unroll
    for (int i = 0; i < 2; ++i) dstg[t + i*256] = srcg[t + i*256];
  }
  #pragma unroll
  for (int mf = 0; mf < 2; ++mf)
    #pragma unroll
    for (int jf = 0; jf < 4; ++jf)
      #pragma unroll
      for (int r = 0; r < 4; ++r) {
        int mm = moff + mf*16 + (l>>4)*4 + r;
        int jc = joff + jf*16 + (l&15);
        int d = jc & 63;
        float v = tanh_fast(acc[mf][jf][r]*s.sc[d] + s.bi[d]);
        s.u.e.xh[jc>>6][d>>3][mm][d&7] = __float2half(v);
      }
  __syncthreads();
  // second GEMM on MFMA: C2[node][dout] = xh(bl) @ ham1, bl = wv&1
  f32x4 acc2[2][4];
  #pragma unroll
  for (int a=0;a<2;++a)
    #pragma unroll
    for (int b=0;b<4;++b) acc2[a][b] = (f32x4){0.f,0.f,0.f,0.f};
  const int gq = l >> 4, cb = l & 15;
  const int blw = wv & 1;
  #pragma unroll
  for (int ks2 = 0; ks2 < 2; ++ks2) {
    half8 a2[2];
    #pragma unroll
    for (int mf = 0; mf < 2; ++mf)
      a2[mf] = *(const half8*)&s.u.e.xh[blw][ks2*4+gq][moff + mf*16 + cb][0];
    #pragma unroll
    for (int jf = 0; jf < 4; ++jf) {
      half8 b2 = *(const half8*)&s.u.e.h1b[ks2*4+gq][jf*16 + cb][0];
      #pragma unroll
      for (int mf = 0; mf < 2; ++mf)
        acc2[mf][jf] = __builtin_amdgcn_mfma_f32_16x16x32_f16(a2[mf], b2, acc2[mf][jf], 0, 0, 0);
    }
  }
  // C2 -> s1l[jout 128][node 72]
  #pragma unroll
  for (int mf = 0; mf < 2; ++mf)
    #pragma unroll
    for (int jf = 0; jf < 4; ++jf)
      #pragma unroll
      for (int r = 0; r < 4; ++r) {
        int node = moff + mf*16 + gq*4 + r;
        int ro = blw*64 + jf*16 + cb;
        s.u.e.s1l[ro][node] = __float2half(acc2[mf][jf][r]);
      }
  __syncthreads();
  // copy out: row jj -> S1T[j0+jj][m0..m0+63]
  {
    int jj = t >> 1, hf = t & 1;
    __half* dst = S1T + (size_t)(j0 + jj)*MSTR + m0 + hf*32;
    const __half* srcl = &s.u.e.s1l[jj][hf*32];
    #pragma unroll
    for (int i = 0; i < 4; ++i)
      if (m0 + hf*32 + i*8 < MSTR)
        *(uint4*)(dst + i*8) = *(const uint4*)(srcl + i*8);
  }
}

// ---------------- GEMM2 (MFMA): X2 = a_n @ S1; epi: BN1+tanh -> feat2 -------
struct SG2 {
  union {
    struct { __half A[2][4][64][8]; __half B[2][4][128][8]; } m;  // 24576B
    struct { __half x2[64][2][72]; } e;                           // 18432B
  } u;
  float sc[64], bi[64];
};

__global__ __launch_bounds__(256) void k_gemm2(
    const __half* __restrict__ anG, const __half* __restrict__ S1T,
    const float* __restrict__ bng, const float* __restrict__ bnb,
    const float* __restrict__ bnm, const float* __restrict__ bnv,
    __half* __restrict__ feat2){
  __shared__ SG2 s;
  const int t = threadIdx.x;
  const int l = t & 63, wv = t >> 6;
  const int xcd = blockIdx.x & 7, idx = blockIdx.x >> 3;
  const int bidj = xcd*96 + idx/5, bidm = idx % 5;
  const int m0 = bidm*64, j0 = bidj*128;
  if (t < 64) {
    float sc = bng[64+t] / sqrtf(bnv[64+t] + 1e-5f);
    s.sc[t] = sc; s.bi[t] = bnb[64+t] - bnm[64+t]*sc;
  }
  const int jB = t >> 1, hB = t & 1;
  const int moff = (wv>>1)*32, joff = (wv&1)*64;

  f32x4 acc[2][4];
  #pragma unroll
  for (int a=0;a<2;++a)
    #pragma unroll
    for (int b=0;b<4;++b) acc[a][b] = (f32x4){0.f,0.f,0.f,0.f};

  {
    uint4 av = *(const uint4*)(anG + (((wv*320) + m0 + l) << 3));
    const __half* bs = S1T + (size_t)(j0 + jB)*MSTR + hB*16;
    uint4 b0 = *(const uint4*)bs;
    uint4 b1 = *(const uint4*)(bs + 8);
    *(uint4*)&s.u.m.A[0][wv][l][0]      = av;
    *(uint4*)&s.u.m.B[0][hB*2][jB][0]   = b0;
    *(uint4*)&s.u.m.B[0][hB*2+1][jB][0] = b1;
  }
  __syncthreads();

  int cur = 0;
  for (int ks = 0; ks < 10; ++ks) {
    uint4 nav, nb0, nb1;
    if (ks < 9) {
      nav = *(const uint4*)(anG + ((((ks+1)*4 + wv)*320 + m0 + l) << 3));
      const __half* bs = S1T + (size_t)(j0 + jB)*MSTR + (ks+1)*32 + hB*16;
      nb0 = *(const uint4*)bs;
      nb1 = *(const uint4*)(bs + 8);
    }
    half8 a8[2], b8[4];
    #pragma unroll
    for (int mf = 0; mf < 2; ++mf)
      a8[mf] = *(const half8*)&s.u.m.A[cur][l>>4][moff + mf*16 + (l&15)][0];
    #pragma unroll
    for (int jf = 0; jf < 4; ++jf)
      b8[jf] = *(const half8*)&s.u.m.B[cur][l>>4][joff + jf*16 + (l&15)][0];
    #pragma unroll
    for (int mf = 0; mf < 2; ++mf)
      #pragma unroll
      for (int jf = 0; jf < 4; ++jf)
        acc[mf][jf] = __builtin_amdgcn_mfma_f32_16x16x32_f16(a8[mf], b8[jf], acc[mf][jf], 0, 0, 0);
    if (ks < 9) {
      *(uint4*)&s.u.m.A[cur^1][wv][l][0]      = nav;
      *(uint4*)&s.u.m.B[cur^1][hB*2][jB][0]   = nb0;
      *(uint4*)&s.u.m.B[cur^1][hB*2+1][jB][0] = nb1;
      __syncthreads();
      cur ^= 1;
    }
  }
  __syncthreads();
  // BN1 + tanh -> x2[m][bl][d]
  #pragma unroll
  for (int mf = 0; mf < 2; ++mf)
    #pragma unroll
    for (int jf = 0; jf < 4; ++jf)
      #pragma unroll
      for (int r = 0; r < 4; ++r) {
        int mm = moff + mf*16 + (l>>4)*4 + r;
        int jc = joff + jf*16 + (l&15);
        int bl = jc >> 6, d = jc & 63;
        float v = tanh_fast(acc[mf][jf][r]*s.sc[d] + s.bi[d]);
        s.u.e.x2[mm][bl][d] = __float2half(v);
      }
  __syncthreads();
  {
    int pr = t >> 1, hf = t & 1;
    int mm = pr >> 1, bl = pr & 1;
    int n = m0 + mm;
    if (n < NND) {
      int jg = j0 + bl*64;
      int b = jg/768, lq = (jg/64)%12;
      __half* dst = feat2 + ((size_t)lq*NROWS + n*BBATCH + b)*F2S + hf*32;
      const __half* srcl = &s.u.e.x2[mm][bl][hf*32];
      #pragma unroll
      for (int i = 0; i < 4; ++i)
        *(uint4*)(dst + i*8) = *(const uint4*)(srcl + i*8);
    }
  }
}

// ---------------- GRU (MFMA, 12 steps) + ReLU + FC head ---------------------
__global__ __launch_bounds__(512, 2) void k_gru(
    const __half* __restrict__ feat2, const __half* __restrict__ wihP,
    const __half* __restrict__ whhP, const float* __restrict__ b_ih,
    const float* __restrict__ b_hh, const float* __restrict__ fc_w,
    const float* __restrict__ fc_b, float* __restrict__ out){
  __shared__ __half wih[10*192*8];
  __shared__ __half whh[8*192*8];
  __shared__ __half xt[10*64*8];
  __shared__ __half Hs[8*64*8];
  __shared__ __half zst[16];
  __shared__ float red[4][2][16];

  const int t = threadIdx.x;
  const int l = t & 63, wv = t >> 6;
  const int mt = wv >> 1, ng = wv & 1;
  const int row0 = blockIdx.x * 64;

  for (int i = t; i < 10*192; i += 512) ((uint4*)wih)[i] = ((const uint4*)wihP)[i];
  for (int i = t; i < 8*192; i += 512)  ((uint4*)whh)[i] = ((const uint4*)whhP)[i];
  for (int i = t; i < 8*64; i += 512)   ((uint4*)Hs)[i] = make_uint4(0,0,0,0);
  if (t < 2) ((uint4*)zst)[t] = make_uint4(0,0,0,0);

  float bR[2], bZ[2], bI[2], bH[2], fw[2];
  #pragma unroll
  for (int s2 = 0; s2 < 2; ++s2) {
    int d = ng*32 + s2*16 + (l & 15);
    bR[s2] = b_ih[d]     + b_hh[d];
    bZ[s2] = b_ih[64+d]  + b_hh[64+d];
    bI[s2] = b_ih[128+d];
    bH[s2] = b_hh[128+d];
    fw[s2] = fc_w[d];
  }
  const float fcb = fc_b[0];
  float hreg[8];
  #pragma unroll
  for (int i = 0; i < 8; ++i) hreg[i] = 0.f;

  const int rst = t >> 3, qst = t & 7;
  {
    const __half* src = feat2 + ((size_t)(row0 + rst))*F2S;
    *(uint4*)&xt[(qst*64 + rst)*8] = *(const uint4*)(src + qst*8);
    if (qst < 2) *(uint4*)&xt[((qst+8)*64 + rst)*8] = *(const uint4*)(src + (qst+8)*8);
  }
  __syncthreads();

  const int rowA = mt*16 + (l & 15);
  const int gq = l >> 4;
  const int colb = l & 15;
  const __half* axt0 = &xt[((0+gq)*64 + rowA)*8];
  const __half* axt1 = &xt[((4+gq)*64 + rowA)*8];
  const __half* axt2 = (gq < 2) ? &xt[((8+gq)*64 + rowA)*8] : zst;
  const __half* ah0  = &Hs[((0+gq)*64 + rowA)*8];
  const __half* ah1  = &Hs[((4+gq)*64 + rowA)*8];
  const __half* bi0  = &wih[((0+gq)*192 + colb)*8];
  const __half* bi1  = &wih[((4+gq)*192 + colb)*8];
  const __half* bi2  = (gq < 2) ? &wih[((8+gq)*192 + colb)*8] : zst;
  const int ntm2 = (gq < 2) ? 128 : 0;
  const __half* bh0  = &whh[((0+gq)*192 + colb)*8];
  const __half* bh1  = &whh[((4+gq)*192 + colb)*8];

  for (int ts = 0; ts < 12; ++ts) {
    half8 agi0 = *(const half8*)axt0;
    half8 agi1 = *(const half8*)axt1;
    half8 agi2 = *(const half8*)axt2;
    half8 agh0 = *(const half8*)ah0;
    half8 agh1 = *(const half8*)ah1;
    f32x4 aR[2], aZ[2], aIn[2], aHn[2];
    #pragma unroll
    for (int s2 = 0; s2 < 2; ++s2) {
      aR[s2] = (f32x4){0.f,0.f,0.f,0.f}; aZ[s2] = (f32x4){0.f,0.f,0.f,0.f};
      aIn[s2] = (f32x4){0.f,0.f,0.f,0.f}; aHn[s2] = (f32x4){0.f,0.f,0.f,0.f};
    }
    #pragma unroll
    for (int s2 = 0; s2 < 2; ++s2) {
      const int ntr = ng*2 + s2, ntz = 4 + ng*2 + s2, ntn = 8 + ng*2 + s2;
      aR[s2] = __builtin_amdgcn_mfma_f32_16x16x32_f16(agi0, *(const half8*)(bi0 + ntr*128), aR[s2], 0,0,0);
      aR[s2] = __builtin_amdgcn_mfma_f32_16x16x32_f16(agi1, *(const half8*)(bi1 + ntr*128), aR[s2], 0,0,0);
      aR[s2] = __builtin_amdgcn_mfma_f32_16x16x32_f16(agi2, *(const half8*)(bi2 + ntr*ntm2), aR[s2], 0,0,0);
      aR[s2] = __builtin_amdgcn_mfma_f32_16x16x32_f16(agh0, *(const half8*)(bh0 + ntr*128), aR[s2], 0,0,0);
      aR[s2] = __builtin_amdgcn_mfma_f32_16x16x32_f16(agh1, *(const half8*)(bh1 + ntr*128), aR[s2], 0,0,0);
      aZ[s2] = __builtin_amdgcn_mfma_f32_16x16x32_f16(agi0, *(const half8*)(bi0 + ntz*128), aZ[s2], 0,0,0);
      aZ[s2] = __builtin_amdgcn_mfma_f32_16x16x32_f16(agi1, *(const half8*)(bi1 + ntz*128), aZ[s2], 0,0,0);
      aZ[s2] = __builtin_amdgcn_mfma_f32_16x16x32_f16(agi2, *(const half8*)(bi2 + ntz*ntm2), aZ[s2], 0,0,0);
      aZ[s2] = __builtin_amdgcn_mfma_f32_16x16x32_f16(agh0, *(const half8*)(bh0 + ntz*128), aZ[s2], 0,0,0);
      aZ[s2] = __builtin_amdgcn_mfma_f32_16x16x32_f16(agh1, *(const half8*)(bh1 + ntz*128), aZ[s2], 0,0,0);
      aIn[s2] = __builtin_amdgcn_mfma_f32_16x16x32_f16(agi0, *(const half8*)(bi0 + ntn*128), aIn[s2], 0,0,0);
      aIn[s2] = __builtin_amdgcn_mfma_f32_16x16x32_f16(agi1, *(const half8*)(bi1 + ntn*128), aIn[s2], 0,0,0);
      aIn[s2] = __builtin_amdgcn_mfma_f32_16x16x32_f16(agi2, *(const half8*)(bi2 + ntn*ntm2), aIn[s2], 0,0,0);
      aHn[s2] = __builtin_amdgcn_mfma_f32_16x16x32_f16(agh0, *(const half8*)(bh0 + ntn*128), aHn[s2], 0,0,0);
      aHn[s2] = __builtin_amdgcn_mfma_f32_16x16x32_f16(agh1, *(const half8*)(bh1 + ntn*128), aHn[s2], 0,0,0);
    }
    float hnew[8];
    #pragma unroll
    for (int s2 = 0; s2 < 2; ++s2)
      #pragma unroll
      for (int rg = 0; rg < 4; ++rg) {
        const int i = s2*4 + rg;
        float pr = aR[s2][rg] + bR[s2];
        float pz = aZ[s2][rg] + bZ[s2];
        float pn = aIn[s2][rg] + bI[s2];
        float ph = aHn[s2][rg] + bH[s2];
        float r = 1.f / (1.f + exp2f(-1.44269504f * pr));
        float z = 1.f / (1.f + exp2f(-1.44269504f * pz));
        float e2 = exp2f(2.88539008f * (pn + r*ph));
        float nc = 1.f - 2.f/(e2 + 1.f);
        hnew[i] = (1.f - z)*nc + z*hreg[i];
        hreg[i] = hnew[i];
      }
    if (ts >= 9) {
      #pragma unroll
      for (int rg = 0; rg < 4; ++rg) {
        float p = fmaxf(hnew[rg],0.f)*fw[0] + fmaxf(hnew[4+rg],0.f)*fw[1];
        p += __shfl_xor(p, 1); p += __shfl_xor(p, 2);
        p += __shfl_xor(p, 4); p += __shfl_xor(p, 8);
        if (colb == 0) red[mt][ng][gq*4 + rg] = p;
      }
    }
    __syncthreads();
    if (ts >= 9 && ng == 0 && colb == 0) {
      #pragma unroll
      for (int rg = 0; rg < 4; ++rg) {
        int rr = gq*4 + rg;
        float sum = red[mt][0][rr] + red[mt][1][rr] + fcb;
        int grow = row0 + mt*16 + rr;
        out[((grow & 127)*3 + (ts-9))*NND + (grow >> 7)] = sum;
      }
    }
    if (ts < 11) {
      #pragma unroll
      for (int s2 = 0; s2 < 2; ++s2) {
        const int d = ng*32 + s2*16 + colb;
        #pragma unroll
        for (int rg = 0; rg < 4; ++rg) {
          int rw = mt*16 + gq*4 + rg;
          Hs[((d>>3)*64 + rw)*8 + (d&7)] = __float2half(hnew[s2*4+rg]);
        }
      }
      const __half* src = feat2 + ((size_t)(ts+1)*NROWS + row0 + rst)*F2S;
      *(uint4*)&xt[(qst*64 + rst)*8] = *(const uint4*)(src + qst*8);
      if (qst < 2) *(uint4*)&xt[((qst+8)*64 + rst)*8] = *(const uint4*)(src + (qst+8)*8);
    }
    __syncthreads();
  }
}

// ---------------------------------------------------------------------------
extern "C" void kernel_launch(void* const* d_in, const int* in_sizes, int n_in,
                              void* d_out, int out_size, void* d_ws, size_t ws_size,
                              hipStream_t stream) {
  const float* hist    = (const float*)d_in[0];
  const float* adj     = (const float*)d_in[1];
  const float* w0      = (const float*)d_in[2];
  const float* w1      = (const float*)d_in[3];
  const float* bng     = (const float*)d_in[4];
  const float* bnb     = (const float*)d_in[5];
  const float* bnm     = (const float*)d_in[6];
  const float* bnv     = (const float*)d_in[7];
  const float* tid_emb = (const float*)d_in[8];
  const float* dw_emb  = (const float*)d_in[9];
  const float* w_ih    = (const float*)d_in[10];
  const float* w_hh    = (const float*)d_in[11];
  const float* b_ih    = (const float*)d_in[12];
  const float* b_hh    = (const float*)d_in[13];
  const float* fc_w    = (const float*)d_in[14];
  const float* fc_b    = (const float*)d_in[15];

  float* wsf   = (float*)d_ws;
  float* dinv  = wsf + OFF_DINV;
  float* ham0T = wsf + OFF_HAM0;
  __half* ham1B = (__half*)(wsf + OFF_HAM1B);
  __half* wihP  = (__half*)(wsf + OFF_WIHP);
  __half* whhP  = (__half*)(wsf + OFF_WHHP);
  __half* anG   = (__half*)(wsf + OFF_ANG);
  __half* S1T   = (__half*)(wsf + OFF_S1T);
  __half* S0T   = (__half*)(wsf + OFF_S0T);
  __half* feat2 = (__half*)(wsf + OFF_FEATH);
  float* outp  = (float*)d_out;

  k_dinv  <<<NND, 64, 0, stream>>>(adj, dinv);
  k_anG   <<<(KPAD*KPAD + 255)/256, 256, 0, stream>>>(adj, dinv, anG);
  k_ham   <<<17, 256, 0, stream>>>(w0, w1, ham0T, ham1B);
  k_wT    <<<108, 256, 0, stream>>>(w_ih, w_hh, wihP, whhP);
  k_s0    <<<BBATCH*LSEQ, 256, 0, stream>>>(hist, ham0T, S0T);
  k_gemm1 <<<5*768, 256, 0, stream>>>(anG, S0T, ham1B, bng, bnb, bnm, bnv, S1T);
  // k_extras AFTER gemm1: feat2 aliases S0T
  k_extras<<<(LSEQ*NROWS + 255)/256, 256, 0, stream>>>(hist, tid_emb, dw_emb, feat2);
  k_gemm2 <<<5*768, 256, 0, stream>>>(anG, S1T, bng, bnb, bnm, bnv, feat2);
  k_gru   <<<NROWS/64, 512, 0, stream>>>(feat2, wihP, whhP, b_ih, b_hh, fc_w, fc_b, outp);
}